// Round 10
// baseline (293.575 us; speedup 1.0000x reference)
//
#include <hip/hip_runtime.h>
#include <hip/hip_bf16.h>
#include <cstdint>

#define D_DIM 1024
#define S_DIM 2048
#define B_DIM 2
#define NROWS 4096
#define H_DIM 16
#define LOG2E 1.4426950408889634f
#define QSCALE (0.125f * LOG2E)

typedef __bf16 bf16x8 __attribute__((ext_vector_type(8)));
typedef float f32x4 __attribute__((ext_vector_type(4)));
typedef unsigned short u16x8 __attribute__((ext_vector_type(8)));

#define MFMA16(a, b, c) __builtin_amdgcn_mfma_f32_16x16x32_bf16(a, b, c, 0, 0, 0)
#define WBAR __builtin_amdgcn_s_barrier()
#define SB0 __builtin_amdgcn_sched_barrier(0)
// rule #18: inline-asm lgkmcnt(0) must be followed by sched_barrier(0)
#define LGKM0 { asm volatile("s_waitcnt lgkmcnt(0)" ::: "memory"); SB0; }
#define VMW(n) asm volatile("s_waitcnt vmcnt(" #n ")" ::: "memory")

__device__ __forceinline__ void async_cp16(const void* g, void* lds) {
  __builtin_amdgcn_global_load_lds(
      (const __attribute__((address_space(1))) void*)(uintptr_t)g,
      (__attribute__((address_space(3))) void*)(uint32_t)(uintptr_t)lds, 16, 0, 0);
}

__device__ __forceinline__ unsigned short f2bf(float f) {
  __hip_bfloat16 h = __float2bfloat16(f);
  return __builtin_bit_cast(unsigned short, h);
}

__device__ __forceinline__ float bf2f(unsigned short u) {
  return __builtin_bit_cast(float, (unsigned int)u << 16);
}

// gelu via sigmoid identity: 0.5*(1+tanh(u)) = 1/(1+exp(-2u)); exp2-space.
__device__ __forceinline__ float gelu_fast(float v) {
  float u = v * v;
  float w = v * fmaf(u, 0.044715f, 1.f);
  float e = exp2f(w * -2.3022161f);  // -2*0.79788456*log2(e)
  return v * __builtin_amdgcn_rcpf(1.f + e);
}

// ---------------- fused weight transpose+cast: 6 matrices in one launch -----
struct TcArgs {
  const float* src[6];
  __hip_bfloat16* dst[6];
  int K[6];
  int N[6];
  int start[6];
};

__global__ __launch_bounds__(256) void transpose_cast6_kernel(TcArgs a) {
  __shared__ float tile[32][33];
  int bid = blockIdx.x, mi = 0;
#pragma unroll
  for (int i = 1; i < 6; i++)
    if (bid >= a.start[i]) mi = i;
  const float* W = a.src[mi];
  __hip_bfloat16* Wt = a.dst[mi];
  int K = a.K[mi], N = a.N[mi];
  int rel = bid - a.start[mi];
  int tilesx = N >> 5;
  int shift = (N == 4096) ? 7 : 5;
  int n0 = (rel & (tilesx - 1)) * 32, k0 = (rel >> shift) * 32;
  int tx = threadIdx.x, ty = threadIdx.y;
#pragma unroll
  for (int i = 0; i < 32; i += 8)
    tile[ty + i][tx] = W[(size_t)(k0 + ty + i) * N + n0 + tx];
  __syncthreads();
#pragma unroll
  for (int i = 0; i < 32; i += 8)
    Wt[(size_t)(n0 + ty + i) * K + k0 + tx] = __float2bfloat16(tile[tx][ty + i]);
}

// ---------------- layernorm (ddof=1) f32 -> bf16 -----------------------------
__global__ __launch_bounds__(256) void ln_kernel(
    const float* __restrict__ x, const float* __restrict__ sc,
    const float* __restrict__ bi, __hip_bfloat16* __restrict__ out) {
  int row = blockIdx.x, t = threadIdx.x;
  float4 v = ((const float4*)(x + (size_t)row * D_DIM))[t];
  float s = v.x + v.y + v.z + v.w;
  float ss = v.x * v.x + v.y * v.y + v.z * v.z + v.w * v.w;
#pragma unroll
  for (int off = 32; off > 0; off >>= 1) {
    s += __shfl_xor(s, off);
    ss += __shfl_xor(ss, off);
  }
  __shared__ float red[8];
  int wid = t >> 6;
  if ((t & 63) == 0) { red[wid] = s; red[4 + wid] = ss; }
  __syncthreads();
  s = red[0] + red[1] + red[2] + red[3];
  ss = red[4] + red[5] + red[6] + red[7];
  float mean = s * (1.f / 1024.f);
  float var = (ss - 1024.f * mean * mean) * (1.f / 1023.f);
  float inv = rsqrtf(var + 1e-5f);
  float4 scv = ((const float4*)sc)[t];
  float4 biv = ((const float4*)bi)[t];
  ushort4 o;
  o.x = f2bf(scv.x * (v.x - mean) * inv + biv.x);
  o.y = f2bf(scv.y * (v.y - mean) * inv + biv.y);
  o.z = f2bf(scv.z * (v.z - mean) * inv + biv.z);
  o.w = f2bf(scv.w * (v.w - mean) * inv + biv.w);
  ((ushort4*)(out + (size_t)row * D_DIM))[t] = o;
}

// ---------------- 128x128 GEMM, deep 2-region K-tiles, 2 blocks/CU -----------
// MODE 0: production. MODE 1: noglobal probe (no stg4/VMW in loop).
// MODE 2: nolds probe (no ds_read/lgkm in loop; frags loaded once).
// MODE 3: mfma+barrier floor probe.
// EPI 0: QKV  EPI 1: gelu->bf16 s4096  EPI 2: bf16 partial s1024  EPI 3: f32+bias+resid
template <int EPI, int MODE = 0>
__global__ __launch_bounds__(256) void gemm128_kernel(
    const __hip_bfloat16* __restrict__ A, const __hip_bfloat16* __restrict__ Bt,
    void* __restrict__ Cout, const float* __restrict__ bias,
    const float* __restrict__ resid, __hip_bfloat16* __restrict__ qb,
    __hip_bfloat16* __restrict__ kb, unsigned short* __restrict__ vt,
    int strideA, int strideB) {
  __shared__ char lds[65536];
  const int t = threadIdx.x;
  const int lane = t & 63, wid = t >> 6;
  const int ql = lane & 15, g = lane >> 4;
  const int wr = wid >> 1, wc = wid & 1;

  // grid decode: bijective XCD chunk -> 4m x 8n groups, column-major groups
  const int nbm = gridDim.x, nby = gridDim.y;
  const int lin = blockIdx.y * nbm + blockIdx.x;
  const int q8 = (nbm * nby) >> 3;
  const int u = (lin & 7) * q8 + (lin >> 3);
  const int gi = u >> 5, wi = u & 31;
  const int gpc = nbm >> 2;
  const int gcol = gi / gpc, grow = gi % gpc;
  const int m0 = (grow * 4 + (wi >> 3)) * 128;
  const int n0 = (gcol * 8 + (wi & 7)) * 128;
  const int koff = blockIdx.z * 1024;
  const int sw = (ql & 7) << 4;

  const int srow = t >> 3;
  const int sc16 = (((t & 7) ^ (srow & 7)) << 4);  // inverse-swizzled src byte
  const __hip_bfloat16* aB = A + (size_t)(m0 + srow) * strideA + koff + (sc16 >> 1);
  const __hip_bfloat16* bB = Bt + (size_t)(n0 + srow) * strideB + koff + (sc16 >> 1);
  const uint32_t ldsT = (uint32_t)(t * 16);

  auto stg4 = [&](int kt, int s) {
#pragma unroll
    for (int p = 0; p < 4; p++)
      async_cp16(aB + (size_t)(p * 32) * strideA + kt * 64,
                 lds + s * 16384 + p * 4096 + ldsT);
#pragma unroll
    for (int p = 0; p < 4; p++)
      async_cp16(bB + (size_t)(p * 32) * strideB + kt * 64,
                 lds + 32768 + s * 16384 + p * 4096 + ldsT);
  };

  bf16x8 aR[4][2], bR[4][2];
  f32x4 acc[4][4] = {};

  auto ldA = [&](int s) {
    const char* base = lds + s * 16384 + (wr * 64 + ql) * 128;
#pragma unroll
    for (int mi = 0; mi < 4; mi++)
#pragma unroll
      for (int kk = 0; kk < 2; kk++)
        aR[mi][kk] = *(const bf16x8*)(base + mi * 2048 + ((kk * 64 + g * 16) ^ sw));
  };
  auto ldB = [&](int s, int nh) {
    const char* base = lds + 32768 + s * 16384 + (wc * 64 + ql) * 128;
#pragma unroll
    for (int ni = 0; ni < 2; ni++)
#pragma unroll
      for (int kk = 0; kk < 2; kk++)
        bR[nh * 2 + ni][kk] =
            *(const bf16x8*)(base + (nh * 2 + ni) * 2048 + ((kk * 64 + g * 16) ^ sw));
  };
  auto mma = [&](int nh) {
    __builtin_amdgcn_s_setprio(1);
#pragma unroll
    for (int mi = 0; mi < 4; mi++)
#pragma unroll
      for (int ni = 0; ni < 2; ni++) {
        f32x4 c = acc[mi][nh * 2 + ni];
        c = MFMA16(aR[mi][0], bR[nh * 2 + ni][0], c);
        c = MFMA16(aR[mi][1], bR[nh * 2 + ni][1], c);
        acc[mi][nh * 2 + ni] = c;
      }
    __builtin_amdgcn_s_setprio(0);
  };

  // prologue: kt0 -> slot0, kt1 -> slot1 (16 loads); VMW(8) -> kt0 resident.
  stg4(0, 0); stg4(1, 1);
  VMW(8); WBAR;

  if constexpr (MODE == 0 || MODE == 1) {
#pragma unroll 1
    for (int kt = 0; kt < 14; ++kt) {
      const int s = kt & 1;
      ldA(s); ldB(s, 0);
      LGKM0; mma(0);
      ldB(s, 1);
      LGKM0; WBAR; SB0;
      if constexpr (MODE == 0) stg4(kt + 2, s);
      mma(1);
      if constexpr (MODE == 0) VMW(8);
      WBAR;
    }
    ldA(0); ldB(0, 0);
    LGKM0; mma(0);
    ldB(0, 1);
    LGKM0; WBAR;
    mma(1);
    if constexpr (MODE == 0) VMW(0);
    WBAR;
    ldA(1); ldB(1, 0);
    LGKM0; mma(0);
    ldB(1, 1);
    LGKM0; mma(1);
  } else if constexpr (MODE == 2) {
    // frags once; keep staging + vmcnt + barrier cadence.
    ldA(0); ldB(0, 0); ldB(0, 1);
    LGKM0;
#pragma unroll 1
    for (int kt = 0; kt < 14; ++kt) {
      const int s = kt & 1;
      mma(0);
      WBAR; SB0;
      stg4(kt + 2, s);
      mma(1);
      VMW(8); WBAR;
    }
    VMW(0);
    mma(0); WBAR; mma(1); WBAR;
    mma(0); WBAR; mma(1);
  } else {
    // MODE 3: MFMA + barriers only.
    ldA(0); ldB(0, 0); ldB(0, 1);
    LGKM0;
#pragma unroll 1
    for (int kt = 0; kt < 16; ++kt) {
      mma(0);
      WBAR;
      mma(1);
      WBAR;
    }
  }

  // ---- epilogue ----
#pragma unroll
  for (int mi = 0; mi < 4; mi++) {
    const int row0 = m0 + wr * 64 + mi * 16 + g * 4;
#pragma unroll
    for (int ni = 0; ni < 4; ni++) {
      const int colt = wc * 64 + ni * 16 + ql;
      const f32x4 c = acc[mi][ni];
      if (EPI == 0) {
        const int seg = n0 >> 10;
        const int c1k = (n0 & 1023) + colt;
        if (seg < 2) {
          __hip_bfloat16* Ob = seg == 0 ? qb : kb;
          const float sc = seg == 0 ? QSCALE : 1.f;
#pragma unroll
          for (int rr = 0; rr < 4; rr++)
            Ob[(size_t)(row0 + rr) * 1024 + c1k] = __float2bfloat16(c[rr] * sc);
        } else {
          const int h = c1k >> 6, dh = c1k & 63;
          const int bb = row0 >> 11, s0 = row0 & 2047;
          ushort4 pk;
          pk.x = f2bf(c[0]); pk.y = f2bf(c[1]); pk.z = f2bf(c[2]); pk.w = f2bf(c[3]);
          *(ushort4*)(vt + (((size_t)(bb * 16 + h) * 64 + dh) << 11) + s0) = pk;
        }
      } else if (EPI == 1) {
        const int col = n0 + colt;
        const float bv = bias[col];
#pragma unroll
        for (int rr = 0; rr < 4; rr++)
          ((__hip_bfloat16*)Cout)[(size_t)(row0 + rr) * 4096 + col] =
              __float2bfloat16(gelu_fast(c[rr] + bv));
      } else if (EPI == 2) {
        unsigned short* Cp = (unsigned short*)Cout + (size_t)blockIdx.z * NROWS * 1024;
        const int col = n0 + colt;
#pragma unroll
        for (int rr = 0; rr < 4; rr++)
          Cp[(size_t)(row0 + rr) * 1024 + col] = f2bf(c[rr]);
      } else {
        const int col = n0 + colt;
        const float bv = bias[col];
#pragma unroll
        for (int rr = 0; rr < 4; rr++)
          ((float*)Cout)[(size_t)(row0 + rr) * 1024 + col] =
              c[rr] + bv + resid[(size_t)(row0 + rr) * 1024 + col];
      }
    }
  }
}

// ---------------- split-K reduce + bias + residual (f32 out) -----------------
__global__ __launch_bounds__(256) void ffn2_reduce_kernel(
    const unsigned short* __restrict__ parts, const float* __restrict__ bias,
    const float* __restrict__ resid, float* __restrict__ out) {
  const size_t i = ((size_t)blockIdx.x * 256 + threadIdx.x) * 8;
  const int col = (int)(i & 1023);
  float a[8];
  float4 r0 = *(const float4*)(resid + i);
  float4 r1 = *(const float4*)(resid + i + 4);
  float4 b0 = *(const float4*)(bias + col);
  float4 b1 = *(const float4*)(bias + col + 4);
  a[0] = r0.x + b0.x; a[1] = r0.y + b0.y; a[2] = r0.z + b0.z; a[3] = r0.w + b0.w;
  a[4] = r1.x + b1.x; a[5] = r1.y + b1.y; a[6] = r1.z + b1.z; a[7] = r1.w + b1.w;
#pragma unroll
  for (int c = 0; c < 4; c++) {
    u16x8 p = *(const u16x8*)(parts + (size_t)c * ((size_t)NROWS * 1024) + i);
#pragma unroll
    for (int j = 0; j < 8; j++) a[j] += bf2f(p[j]);
  }
  float4 o0 = {a[0], a[1], a[2], a[3]};
  float4 o1 = {a[4], a[5], a[6], a[7]};
  *(float4*)(out + i) = o0;
  *(float4*)(out + i + 4) = o1;
}

// ---------------- causal flash attention, LDS-staged K/V (unchanged) ---------
__global__ __launch_bounds__(256) void attn_kernel(
    const __hip_bfloat16* __restrict__ Q, const __hip_bfloat16* __restrict__ Kb,
    const __hip_bfloat16* __restrict__ Vt, __hip_bfloat16* __restrict__ ctx) {
  __shared__ unsigned short Ks[2][64 * 64];
  __shared__ unsigned short Vs[2][64 * 64];
  __shared__ alignas(16) unsigned short Ps[4][16 * 64];
  const int t = threadIdx.x;
  const int lane = t & 63, wid = t >> 6;
  const int ql = lane & 15, g = lane >> 4;
  const int bid = blockIdx.x;
  const int r4 = bid >> 8, k8 = (bid >> 5) & 7, bh = bid & 31;
  const int qt = (r4 == 0) ? 31 - k8 : (r4 == 1) ? 16 + k8 : (r4 == 2) ? 15 - k8 : k8;
  const int b = bh >> 4, hh = bh & 15;
  const int wq0 = qt * 64 + wid * 16;
  const __hip_bfloat16* qp = Q + (size_t)b * S_DIM * D_DIM + hh * 64;
  const __hip_bfloat16* kp = Kb + (size_t)b * S_DIM * D_DIM + hh * 64;
  const __hip_bfloat16* vp = Vt + (size_t)bh * 64 * S_DIM;
  const int kvend = qt * 64 + 64;
  const int swz = (ql & 7) << 4;
  const f32x4 z4 = {0.f, 0.f, 0.f, 0.f};

  auto stageKV = [&](int buf, int kv0) {
    const int sub = lane >> 3, c = lane & 7;
#pragma unroll
    for (int i = 0; i < 2; i++) {
      const int row = wid * 16 + i * 8 + sub;
      const int cs = (c ^ (row & 7)) * 8;
      async_cp16(kp + (size_t)(kv0 + row) * D_DIM + cs,
                 (char*)&Ks[buf][0] + (wid * 16 + i * 8) * 128);
      async_cp16(vp + (size_t)row * S_DIM + kv0 + cs,
                 (char*)&Vs[buf][0] + (wid * 16 + i * 8) * 128);
    }
  };

  bf16x8 qf[2];
#pragma unroll
  for (int hf = 0; hf < 2; hf++)
    qf[hf] = *(const bf16x8*)(qp + (size_t)(wq0 + ql) * D_DIM + hf * 32 + g * 8);

  float m = -3.0e38f, lsum = 0.f;
  f32x4 acc[4] = {};
  unsigned short* Pw = Ps[wid];

  stageKV(0, 0);
  __syncthreads();
  int cur = 0;
  for (int kv0 = 0; kv0 < kvend; kv0 += 64) {
    if (kv0 + 64 < kvend) stageKV(cur ^ 1, kv0 + 64);

    if (kv0 <= wq0 + 15) {
      const char* Kt = (const char*)&Ks[cur][0];
      f32x4 st[4];
#pragma unroll
      for (int ks = 0; ks < 4; ks++) {
        bf16x8 k0 = *(const bf16x8*)(Kt + (ks * 16 + ql) * 128 + ((g * 16) ^ swz));
        bf16x8 k1 = *(const bf16x8*)(Kt + (ks * 16 + ql) * 128 + (((4 + g) * 16) ^ swz));
        st[ks] = MFMA16(k1, qf[1], MFMA16(k0, qf[0], z4));
      }
      if (kv0 + 63 > wq0) {
#pragma unroll
        for (int ks = 0; ks < 4; ks++)
#pragma unroll
          for (int r = 0; r < 4; r++)
            if (kv0 + ks * 16 + 4 * g + r > wq0 + ql) st[ks][r] = -3.0e38f;
      }
      float tm = -3.0e38f;
#pragma unroll
      for (int ks = 0; ks < 4; ks++)
#pragma unroll
        for (int r = 0; r < 4; r++) tm = fmaxf(tm, st[ks][r]);
      tm = fmaxf(tm, __shfl_xor(tm, 16));
      tm = fmaxf(tm, __shfl_xor(tm, 32));
      if (!__all(tm <= m + 8.f)) {
        const float mn = fmaxf(m, tm);
        const float alpha = exp2f(m - mn);
        lsum *= alpha;
#pragma unroll
        for (int db = 0; db < 4; db++) acc[db] *= alpha;
        m = mn;
      }
      float psum = 0.f;
#pragma unroll
      for (int ks = 0; ks < 4; ks++) {
        float p0 = exp2f(st[ks][0] - m), p1 = exp2f(st[ks][1] - m);
        float p2 = exp2f(st[ks][2] - m), p3 = exp2f(st[ks][3] - m);
        psum += (p0 + p1) + (p2 + p3);
        ushort4 pk;
        pk.x = f2bf(p0); pk.y = f2bf(p1); pk.z = f2bf(p2); pk.w = f2bf(p3);
        *(ushort4*)((char*)Pw + ql * 128 + ((ks * 32 + 8 * g) ^ swz)) = pk;
      }
      psum += __shfl_xor(psum, 16);
      psum += __shfl_xor(psum, 32);
      lsum += psum;

      const char* Vtl = (const char*)&Vs[cur][0];
#pragma unroll
      for (int ksl = 0; ksl < 2; ksl++) {
        bf16x8 pb = *(const bf16x8*)((const char*)Pw + ql * 128 + ((ksl * 64 + 16 * g) ^ swz));
#pragma unroll
        for (int db = 0; db < 4; db++) {
          bf16x8 va = *(const bf16x8*)(Vtl + (db * 16 + ql) * 128 + (((ksl * 4 + g) * 16) ^ swz));
          acc[db] = MFMA16(va, pb, acc[db]);
        }
      }
    }
    __syncthreads();
    cur ^= 1;
  }

  const float inv = 1.f / lsum;
  unsigned short* cp = (unsigned short*)ctx + (size_t)(b * S_DIM + wq0 + ql) * D_DIM + hh * 64;
#pragma unroll
  for (int db = 0; db < 4; db++)
#pragma unroll
    for (int i = 0; i < 2; i++) {
      unsigned int lo = f2bf(acc[db][2 * i] * inv);
      unsigned int hi = f2bf(acc[db][2 * i + 1] * inv);
      *(unsigned int*)(cp + db * 16 + 4 * g + 2 * i) = lo | (hi << 16);
    }
}

// ---------------- orchestration ----------------------------------------------
extern "C" void kernel_launch(void* const* d_in, const int* in_sizes, int n_in,
                              void* d_out, int out_size, void* d_ws, size_t ws_size,
                              hipStream_t stream) {
  const float* x = (const float*)d_in[0];
  const float* Wq = (const float*)d_in[1];
  const float* Wk = (const float*)d_in[2];
  const float* Wv = (const float*)d_in[3];
  const float* Wo = (const float*)d_in[4];
  const float* bo = (const float*)d_in[5];
  const float* W1 = (const float*)d_in[6];
  const float* b1 = (const float*)d_in[7];
  const float* W2 = (const float*)d_in[8];
  const float* b2 = (const float*)d_in[9];
  const float* ln1s = (const float*)d_in[10];
  const float* ln1b = (const float*)d_in[11];
  const float* ln2s = (const float*)d_in[12];
  const float* ln2b = (const float*)d_in[13];
  float* out = (float*)d_out;

  char* p = (char*)d_ws;
  auto take = [&](size_t n) { char* r = p; p += (n + 255) & ~(size_t)255; return r; };
  __hip_bfloat16* Wqt = (__hip_bfloat16*)take((size_t)1024 * 1024 * 2);
  __hip_bfloat16* Wkt = (__hip_bfloat16*)take((size_t)1024 * 1024 * 2);
  __hip_bfloat16* Wvt = (__hip_bfloat16*)take((size_t)1024 * 1024 * 2);
  __hip_bfloat16* Wot = (__hip_bfloat16*)take((size_t)1024 * 1024 * 2);
  __hip_bfloat16* W1t = (__hip_bfloat16*)take((size_t)4096 * 1024 * 2);
  __hip_bfloat16* W2t = (__hip_bfloat16*)take((size_t)4096 * 1024 * 2);
  __hip_bfloat16* hbuf = (__hip_bfloat16*)take((size_t)NROWS * 1024 * 2);
  __hip_bfloat16* qbuf = (__hip_bfloat16*)take((size_t)NROWS * 1024 * 2);
  __hip_bfloat16* kbuf = (__hip_bfloat16*)take((size_t)NROWS * 1024 * 2);
  __hip_bfloat16* vtbuf = (__hip_bfloat16*)take((size_t)NROWS * 1024 * 2);
  __hip_bfloat16* ctxbuf = (__hip_bfloat16*)take((size_t)NROWS * 1024 * 2);
  float* x1buf = (float*)take((size_t)NROWS * 1024 * 4);
  __hip_bfloat16* h2buf = (__hip_bfloat16*)take((size_t)NROWS * 1024 * 2);
  __hip_bfloat16* gbuf = (__hip_bfloat16*)take((size_t)NROWS * 4096 * 2);
  unsigned short* parts = (unsigned short*)hbuf;

  TcArgs ta;
  ta.src[0] = Wq;  ta.dst[0] = Wqt;  ta.K[0] = 1024; ta.N[0] = 1024; ta.start[0] = 0;
  ta.src[1] = Wk;  ta.dst[1] = Wkt;  ta.K[1] = 1024; ta.N[1] = 1024; ta.start[1] = 1024;
  ta.src[2] = Wv;  ta.dst[2] = Wvt;  ta.K[2] = 1024; ta.N[2] = 1024; ta.start[2] = 2048;
  ta.src[3] = Wo;  ta.dst[3] = Wot;  ta.K[3] = 1024; ta.N[3] = 1024; ta.start[3] = 3072;
  ta.src[4] = W1;  ta.dst[4] = W1t;  ta.K[4] = 1024; ta.N[4] = 4096; ta.start[4] = 4096;
  ta.src[5] = W2;  ta.dst[5] = W2t;  ta.K[5] = 4096; ta.N[5] = 1024; ta.start[5] = 8192;
  transpose_cast6_kernel<<<12288, dim3(32, 8), 0, stream>>>(ta);

  ln_kernel<<<NROWS, 256, 0, stream>>>(x, ln1s, ln1b, hbuf);

  gemm128_kernel<0><<<dim3(32, 24), 256, 0, stream>>>(
      hbuf, Wqt, nullptr, nullptr, nullptr, qbuf, kbuf, (unsigned short*)vtbuf,
      1024, 1024);

  attn_kernel<<<1024, 256, 0, stream>>>(qbuf, kbuf, vtbuf, ctxbuf);

  gemm128_kernel<3><<<dim3(32, 8), 256, 0, stream>>>(
      ctxbuf, Wot, x1buf, bo, x, nullptr, nullptr, nullptr, 1024, 1024);

  ln_kernel<<<NROWS, 256, 0, stream>>>(x1buf, ln2s, ln2b, h2buf);

  gemm128_kernel<1><<<dim3(32, 32), 256, 0, stream>>>(
      h2buf, W1t, gbuf, b1, nullptr, nullptr, nullptr, nullptr, 1024, 1024);

  gemm128_kernel<2><<<dim3(32, 8, 4), 256, 0, stream>>>(
      gbuf, W2t, parts, nullptr, nullptr, nullptr, nullptr, nullptr, 4096, 4096);

  ffn2_reduce_kernel<<<2048, 256, 0, stream>>>(parts, b2, x1buf, out);

  // ---- ablation probes (outputs -> dead gbuf; FFN1 shape; MODE templated) ----
  gemm128_kernel<2, 1><<<dim3(32, 32), 256, 0, stream>>>(   // P1 noglobal
      h2buf, W1t, gbuf, b1, nullptr, nullptr, nullptr, nullptr, 1024, 1024);
  gemm128_kernel<2, 2><<<dim3(32, 32), 256, 0, stream>>>(   // P2 nolds
      h2buf, W1t, gbuf, b1, nullptr, nullptr, nullptr, nullptr, 1024, 1024);
  gemm128_kernel<2, 3><<<dim3(32, 32), 256, 0, stream>>>(   // P3 mfma floor
      h2buf, W1t, gbuf, b1, nullptr, nullptr, nullptr, nullptr, 1024, 1024);
}

// Round 11
// 255.879 us; speedup vs baseline: 1.1473x; 1.1473x over previous
//
#include <hip/hip_runtime.h>
#include <hip/hip_bf16.h>
#include <cstdint>

#define D_DIM 1024
#define S_DIM 2048
#define B_DIM 2
#define NROWS 4096
#define H_DIM 16
#define LOG2E 1.4426950408889634f
#define QSCALE (0.125f * LOG2E)

typedef __bf16 bf16x8 __attribute__((ext_vector_type(8)));
typedef float f32x4 __attribute__((ext_vector_type(4)));
typedef unsigned short u16x8 __attribute__((ext_vector_type(8)));

#define MFMA16(a, b, c) __builtin_amdgcn_mfma_f32_16x16x32_bf16(a, b, c, 0, 0, 0)

__device__ __forceinline__ void async_cp16(const void* g, void* lds) {
  __builtin_amdgcn_global_load_lds(
      (const __attribute__((address_space(1))) void*)(uintptr_t)g,
      (__attribute__((address_space(3))) void*)(uint32_t)(uintptr_t)lds, 16, 0, 0);
}

__device__ __forceinline__ unsigned short f2bf(float f) {
  __hip_bfloat16 h = __float2bfloat16(f);
  return __builtin_bit_cast(unsigned short, h);
}

__device__ __forceinline__ float bf2f(unsigned short u) {
  return __builtin_bit_cast(float, (unsigned int)u << 16);
}

// gelu via sigmoid identity: 0.5*(1+tanh(u)) = 1/(1+exp(-2u)); exp2-space.
__device__ __forceinline__ float gelu_fast(float v) {
  float u = v * v;
  float w = v * fmaf(u, 0.044715f, 1.f);
  float e = exp2f(w * -2.3022161f);  // -2*0.79788456*log2(e)
  return v * __builtin_amdgcn_rcpf(1.f + e);
}

// ---------------- fused weight transpose+cast: 6 matrices in one launch -----
struct TcArgs {
  const float* src[6];
  __hip_bfloat16* dst[6];
  int K[6];
  int N[6];
  int start[6];
};

__global__ __launch_bounds__(256) void transpose_cast6_kernel(TcArgs a) {
  __shared__ float tile[32][33];
  int bid = blockIdx.x, mi = 0;
#pragma unroll
  for (int i = 1; i < 6; i++)
    if (bid >= a.start[i]) mi = i;
  const float* W = a.src[mi];
  __hip_bfloat16* Wt = a.dst[mi];
  int K = a.K[mi], N = a.N[mi];
  int rel = bid - a.start[mi];
  int tilesx = N >> 5;
  int shift = (N == 4096) ? 7 : 5;
  int n0 = (rel & (tilesx - 1)) * 32, k0 = (rel >> shift) * 32;
  int tx = threadIdx.x, ty = threadIdx.y;
#pragma unroll
  for (int i = 0; i < 32; i += 8)
    tile[ty + i][tx] = W[(size_t)(k0 + ty + i) * N + n0 + tx];
  __syncthreads();
#pragma unroll
  for (int i = 0; i < 32; i += 8)
    Wt[(size_t)(n0 + ty + i) * K + k0 + tx] = __float2bfloat16(tile[tx][ty + i]);
}

// ---------------- layernorm (ddof=1) f32 -> bf16 -----------------------------
__global__ __launch_bounds__(256) void ln_kernel(
    const float* __restrict__ x, const float* __restrict__ sc,
    const float* __restrict__ bi, __hip_bfloat16* __restrict__ out) {
  int row = blockIdx.x, t = threadIdx.x;
  float4 v = ((const float4*)(x + (size_t)row * D_DIM))[t];
  float s = v.x + v.y + v.z + v.w;
  float ss = v.x * v.x + v.y * v.y + v.z * v.z + v.w * v.w;
#pragma unroll
  for (int off = 32; off > 0; off >>= 1) {
    s += __shfl_xor(s, off);
    ss += __shfl_xor(ss, off);
  }
  __shared__ float red[8];
  int wid = t >> 6;
  if ((t & 63) == 0) { red[wid] = s; red[4 + wid] = ss; }
  __syncthreads();
  s = red[0] + red[1] + red[2] + red[3];
  ss = red[4] + red[5] + red[6] + red[7];
  float mean = s * (1.f / 1024.f);
  float var = (ss - 1024.f * mean * mean) * (1.f / 1023.f);
  float inv = rsqrtf(var + 1e-5f);
  float4 scv = ((const float4*)sc)[t];
  float4 biv = ((const float4*)bi)[t];
  ushort4 o;
  o.x = f2bf(scv.x * (v.x - mean) * inv + biv.x);
  o.y = f2bf(scv.y * (v.y - mean) * inv + biv.y);
  o.z = f2bf(scv.z * (v.z - mean) * inv + biv.z);
  o.w = f2bf(scv.w * (v.w - mean) * inv + biv.w);
  ((ushort4*)(out + (size_t)row * D_DIM))[t] = o;
}

// ---------------- 128x128 GEMM, m97 structure: BK=32, dbuf, 2 barriers -------
// 4 waves, 32 KB LDS, ~72-90 VGPR -> 4 blocks/CU co-resident (m114 TLP:
// while one block drains vmcnt at its barrier, other blocks' waves issue).
// Compiler-managed waitcnt (no inline asm). Bijective XCD swizzle.
// EPI 0: QKV (col 0..3071: Q*=QSCALE->qb, K->kb, V transposed -> vt[b,h,d,s])
// EPI 1: f32 + bias + resid (Wo), N=1024
// EPI 2: gelu_fast(v+bias) -> bf16, N=4096 (FFN1)
// EPI 3: bf16 partial kz -> parts + kz*4096*1024 (FFN2 split-K)
template <int EPI>
__global__ __launch_bounds__(256) void gemm_bt_kernel(
    const __hip_bfloat16* __restrict__ A, const __hip_bfloat16* __restrict__ Bt,
    void* __restrict__ Cout, const float* __restrict__ bias,
    const float* __restrict__ resid, __hip_bfloat16* __restrict__ qb,
    __hip_bfloat16* __restrict__ kb, unsigned short* __restrict__ vt,
    int K, int kchunk) {
  __shared__ __hip_bfloat16 As[2][128 * 32];
  __shared__ __hip_bfloat16 Bs[2][128 * 32];
  const int t = threadIdx.x;
  const int lane = t & 63, wid = t >> 6;
  const int ql = lane & 15, g = lane >> 4;
  // bijective XCD swizzle (all grids have nwg % 8 == 0); u fastest in m.
  const int nbx = gridDim.x;
  const int nwg = nbx * gridDim.y;
  const int lin = blockIdx.y * nbx + blockIdx.x;
  const int cpx = nwg >> 3;
  const int u = (lin & 7) * cpx + (lin >> 3);
  const int m0 = (u % nbx) * 128, n0 = (u / nbx) * 128;
  const int kz = blockIdx.z;
  const int wm = (wid >> 1) * 64, wn = (wid & 1) * 64;
  f32x4 acc[4][4] = {};
  const int sr = t >> 2, sc8 = (t & 3) * 8;
  const __hip_bfloat16* ag = A + (size_t)(m0 + sr) * K + sc8 + (size_t)kz * kchunk;
  const __hip_bfloat16* bg = Bt + (size_t)(n0 + sr) * K + sc8 + (size_t)kz * kchunk;

  auto stage = [&](int buf, int k0) {
    async_cp16(ag + k0, (char*)&As[buf][0] + wid * 1024);
    async_cp16(ag + (size_t)64 * K + k0, (char*)&As[buf][0] + 4096 + wid * 1024);
    async_cp16(bg + k0, (char*)&Bs[buf][0] + wid * 1024);
    async_cp16(bg + (size_t)64 * K + k0, (char*)&Bs[buf][0] + 4096 + wid * 1024);
  };
  auto compute = [&](int buf) {
    bf16x8 af[4], bfr[4];
#pragma unroll
    for (int mb = 0; mb < 4; mb++)
      af[mb] = *(const bf16x8*)(&As[buf][(wm + mb * 16 + ql) * 32 + g * 8]);
#pragma unroll
    for (int nb = 0; nb < 4; nb++)
      bfr[nb] = *(const bf16x8*)(&Bs[buf][(wn + nb * 16 + ql) * 32 + g * 8]);
#pragma unroll
    for (int mb = 0; mb < 4; mb++)
#pragma unroll
      for (int nb = 0; nb < 4; nb++)
        acc[mb][nb] = MFMA16(af[mb], bfr[nb], acc[mb][nb]);
  };

  stage(0, 0);
  __syncthreads();  // compiler drains vmcnt before barrier -> tile 0 resident
  const int nsteps = kchunk >> 5;
  int cur = 0;
  for (int s = 0; s < nsteps - 1; ++s) {
    stage(cur ^ 1, (s + 1) * 32);  // prefetch next while computing this
    compute(cur);
    __syncthreads();
    cur ^= 1;
  }
  compute(cur);

  // ---- epilogue ----
  const int rb = m0 + wm + (g << 2);
#pragma unroll
  for (int mb = 0; mb < 4; mb++) {
#pragma unroll
    for (int nb = 0; nb < 4; nb++) {
      const int col = n0 + wn + nb * 16 + ql;
      const f32x4 c = acc[mb][nb];
      const int row0 = rb + mb * 16;
      if (EPI == 0) {
        const int seg = col >> 10;
        const int c1k = col & 1023;
        if (seg < 2) {
          __hip_bfloat16* Ob = seg == 0 ? qb : kb;
          const float sc = seg == 0 ? QSCALE : 1.f;
#pragma unroll
          for (int rr = 0; rr < 4; rr++)
            Ob[(size_t)(row0 + rr) * 1024 + c1k] = __float2bfloat16(c[rr] * sc);
        } else {
          const int h = c1k >> 6, dh = c1k & 63;
          const int bb = row0 >> 11, s0 = row0 & 2047;
          ushort4 pk;
          pk.x = f2bf(c[0]); pk.y = f2bf(c[1]); pk.z = f2bf(c[2]); pk.w = f2bf(c[3]);
          *(ushort4*)(vt + (((size_t)(bb * 16 + h) * 64 + dh) << 11) + s0) = pk;
        }
      } else if (EPI == 1) {
        const float bv = bias[col];
#pragma unroll
        for (int rr = 0; rr < 4; rr++)
          ((float*)Cout)[(size_t)(row0 + rr) * 1024 + col] =
              c[rr] + bv + resid[(size_t)(row0 + rr) * 1024 + col];
      } else if (EPI == 2) {
        const float bv = bias[col];
#pragma unroll
        for (int rr = 0; rr < 4; rr++)
          ((__hip_bfloat16*)Cout)[(size_t)(row0 + rr) * 4096 + col] =
              __float2bfloat16(gelu_fast(c[rr] + bv));
      } else {
        unsigned short* Cp = (unsigned short*)Cout + (size_t)kz * NROWS * 1024;
#pragma unroll
        for (int rr = 0; rr < 4; rr++)
          Cp[(size_t)(row0 + rr) * 1024 + col] = f2bf(c[rr]);
      }
    }
  }
}

// ---------------- split-K reduce + bias + residual (f32 out) -----------------
__global__ __launch_bounds__(256) void ffn2_reduce_kernel(
    const unsigned short* __restrict__ parts, const float* __restrict__ bias,
    const float* __restrict__ resid, float* __restrict__ out) {
  const size_t i = ((size_t)blockIdx.x * 256 + threadIdx.x) * 8;
  const int col = (int)(i & 1023);
  float a[8];
  float4 r0 = *(const float4*)(resid + i);
  float4 r1 = *(const float4*)(resid + i + 4);
  float4 b0 = *(const float4*)(bias + col);
  float4 b1 = *(const float4*)(bias + col + 4);
  a[0] = r0.x + b0.x; a[1] = r0.y + b0.y; a[2] = r0.z + b0.z; a[3] = r0.w + b0.w;
  a[4] = r1.x + b1.x; a[5] = r1.y + b1.y; a[6] = r1.z + b1.z; a[7] = r1.w + b1.w;
#pragma unroll
  for (int c = 0; c < 4; c++) {
    u16x8 p = *(const u16x8*)(parts + (size_t)c * ((size_t)NROWS * 1024) + i);
#pragma unroll
    for (int j = 0; j < 8; j++) a[j] += bf2f(p[j]);
  }
  float4 o0 = {a[0], a[1], a[2], a[3]};
  float4 o1 = {a[4], a[5], a[6], a[7]};
  *(float4*)(out + i) = o0;
  *(float4*)(out + i + 4) = o1;
}

// ---------------- causal flash attention, LDS-staged K/V (unchanged) ---------
__global__ __launch_bounds__(256) void attn_kernel(
    const __hip_bfloat16* __restrict__ Q, const __hip_bfloat16* __restrict__ Kb,
    const __hip_bfloat16* __restrict__ Vt, __hip_bfloat16* __restrict__ ctx) {
  __shared__ unsigned short Ks[2][64 * 64];
  __shared__ unsigned short Vs[2][64 * 64];
  __shared__ alignas(16) unsigned short Ps[4][16 * 64];
  const int t = threadIdx.x;
  const int lane = t & 63, wid = t >> 6;
  const int ql = lane & 15, g = lane >> 4;
  const int bid = blockIdx.x;
  const int r4 = bid >> 8, k8 = (bid >> 5) & 7, bh = bid & 31;
  const int qt = (r4 == 0) ? 31 - k8 : (r4 == 1) ? 16 + k8 : (r4 == 2) ? 15 - k8 : k8;
  const int b = bh >> 4, hh = bh & 15;
  const int wq0 = qt * 64 + wid * 16;
  const __hip_bfloat16* qp = Q + (size_t)b * S_DIM * D_DIM + hh * 64;
  const __hip_bfloat16* kp = Kb + (size_t)b * S_DIM * D_DIM + hh * 64;
  const __hip_bfloat16* vp = Vt + (size_t)bh * 64 * S_DIM;
  const int kvend = qt * 64 + 64;
  const int swz = (ql & 7) << 4;
  const f32x4 z4 = {0.f, 0.f, 0.f, 0.f};

  auto stageKV = [&](int buf, int kv0) {
    const int sub = lane >> 3, c = lane & 7;
#pragma unroll
    for (int i = 0; i < 2; i++) {
      const int row = wid * 16 + i * 8 + sub;
      const int cs = (c ^ (row & 7)) * 8;
      async_cp16(kp + (size_t)(kv0 + row) * D_DIM + cs,
                 (char*)&Ks[buf][0] + (wid * 16 + i * 8) * 128);
      async_cp16(vp + (size_t)row * S_DIM + kv0 + cs,
                 (char*)&Vs[buf][0] + (wid * 16 + i * 8) * 128);
    }
  };

  bf16x8 qf[2];
#pragma unroll
  for (int hf = 0; hf < 2; hf++)
    qf[hf] = *(const bf16x8*)(qp + (size_t)(wq0 + ql) * D_DIM + hf * 32 + g * 8);

  float m = -3.0e38f, lsum = 0.f;
  f32x4 acc[4] = {};
  unsigned short* Pw = Ps[wid];

  stageKV(0, 0);
  __syncthreads();
  int cur = 0;
  for (int kv0 = 0; kv0 < kvend; kv0 += 64) {
    if (kv0 + 64 < kvend) stageKV(cur ^ 1, kv0 + 64);

    if (kv0 <= wq0 + 15) {
      const char* Kt = (const char*)&Ks[cur][0];
      f32x4 st[4];
#pragma unroll
      for (int ks = 0; ks < 4; ks++) {
        bf16x8 k0 = *(const bf16x8*)(Kt + (ks * 16 + ql) * 128 + ((g * 16) ^ swz));
        bf16x8 k1 = *(const bf16x8*)(Kt + (ks * 16 + ql) * 128 + (((4 + g) * 16) ^ swz));
        st[ks] = MFMA16(k1, qf[1], MFMA16(k0, qf[0], z4));
      }
      if (kv0 + 63 > wq0) {
#pragma unroll
        for (int ks = 0; ks < 4; ks++)
#pragma unroll
          for (int r = 0; r < 4; r++)
            if (kv0 + ks * 16 + 4 * g + r > wq0 + ql) st[ks][r] = -3.0e38f;
      }
      float tm = -3.0e38f;
#pragma unroll
      for (int ks = 0; ks < 4; ks++)
#pragma unroll
        for (int r = 0; r < 4; r++) tm = fmaxf(tm, st[ks][r]);
      tm = fmaxf(tm, __shfl_xor(tm, 16));
      tm = fmaxf(tm, __shfl_xor(tm, 32));
      if (!__all(tm <= m + 8.f)) {
        const float mn = fmaxf(m, tm);
        const float alpha = exp2f(m - mn);
        lsum *= alpha;
#pragma unroll
        for (int db = 0; db < 4; db++) acc[db] *= alpha;
        m = mn;
      }
      float psum = 0.f;
#pragma unroll
      for (int ks = 0; ks < 4; ks++) {
        float p0 = exp2f(st[ks][0] - m), p1 = exp2f(st[ks][1] - m);
        float p2 = exp2f(st[ks][2] - m), p3 = exp2f(st[ks][3] - m);
        psum += (p0 + p1) + (p2 + p3);
        ushort4 pk;
        pk.x = f2bf(p0); pk.y = f2bf(p1); pk.z = f2bf(p2); pk.w = f2bf(p3);
        *(ushort4*)((char*)Pw + ql * 128 + ((ks * 32 + 8 * g) ^ swz)) = pk;
      }
      psum += __shfl_xor(psum, 16);
      psum += __shfl_xor(psum, 32);
      lsum += psum;

      const char* Vtl = (const char*)&Vs[cur][0];
#pragma unroll
      for (int ksl = 0; ksl < 2; ksl++) {
        bf16x8 pb = *(const bf16x8*)((const char*)Pw + ql * 128 + ((ksl * 64 + 16 * g) ^ swz));
#pragma unroll
        for (int db = 0; db < 4; db++) {
          bf16x8 va = *(const bf16x8*)(Vtl + (db * 16 + ql) * 128 + (((ksl * 4 + g) * 16) ^ swz));
          acc[db] = MFMA16(va, pb, acc[db]);
        }
      }
    }
    __syncthreads();
    cur ^= 1;
  }

  const float inv = 1.f / lsum;
  unsigned short* cp = (unsigned short*)ctx + (size_t)(b * S_DIM + wq0 + ql) * D_DIM + hh * 64;
#pragma unroll
  for (int db = 0; db < 4; db++)
#pragma unroll
    for (int i = 0; i < 2; i++) {
      unsigned int lo = f2bf(acc[db][2 * i] * inv);
      unsigned int hi = f2bf(acc[db][2 * i + 1] * inv);
      *(unsigned int*)(cp + db * 16 + 4 * g + 2 * i) = lo | (hi << 16);
    }
}

// ---------------- orchestration ----------------------------------------------
extern "C" void kernel_launch(void* const* d_in, const int* in_sizes, int n_in,
                              void* d_out, int out_size, void* d_ws, size_t ws_size,
                              hipStream_t stream) {
  const float* x = (const float*)d_in[0];
  const float* Wq = (const float*)d_in[1];
  const float* Wk = (const float*)d_in[2];
  const float* Wv = (const float*)d_in[3];
  const float* Wo = (const float*)d_in[4];
  const float* bo = (const float*)d_in[5];
  const float* W1 = (const float*)d_in[6];
  const float* b1 = (const float*)d_in[7];
  const float* W2 = (const float*)d_in[8];
  const float* b2 = (const float*)d_in[9];
  const float* ln1s = (const float*)d_in[10];
  const float* ln1b = (const float*)d_in[11];
  const float* ln2s = (const float*)d_in[12];
  const float* ln2b = (const float*)d_in[13];
  float* out = (float*)d_out;

  char* p = (char*)d_ws;
  auto take = [&](size_t n) { char* r = p; p += (n + 255) & ~(size_t)255; return r; };
  // Wqt/Wkt/Wvt contiguous -> one [3072][1024] B^T for the fused QKV GEMM.
  __hip_bfloat16* Wqt = (__hip_bfloat16*)take((size_t)1024 * 1024 * 2);
  __hip_bfloat16* Wkt = (__hip_bfloat16*)take((size_t)1024 * 1024 * 2);
  __hip_bfloat16* Wvt = (__hip_bfloat16*)take((size_t)1024 * 1024 * 2);
  __hip_bfloat16* Wot = (__hip_bfloat16*)take((size_t)1024 * 1024 * 2);
  __hip_bfloat16* W1t = (__hip_bfloat16*)take((size_t)4096 * 1024 * 2);
  __hip_bfloat16* W2t = (__hip_bfloat16*)take((size_t)4096 * 1024 * 2);
  __hip_bfloat16* hbuf = (__hip_bfloat16*)take((size_t)NROWS * 1024 * 2);
  __hip_bfloat16* qbuf = (__hip_bfloat16*)take((size_t)NROWS * 1024 * 2);
  __hip_bfloat16* kbuf = (__hip_bfloat16*)take((size_t)NROWS * 1024 * 2);
  __hip_bfloat16* vtbuf = (__hip_bfloat16*)take((size_t)NROWS * 1024 * 2);
  __hip_bfloat16* ctxbuf = (__hip_bfloat16*)take((size_t)NROWS * 1024 * 2);
  float* x1buf = (float*)take((size_t)NROWS * 1024 * 4);
  __hip_bfloat16* h2buf = (__hip_bfloat16*)take((size_t)NROWS * 1024 * 2);
  __hip_bfloat16* gbuf = (__hip_bfloat16*)take((size_t)NROWS * 4096 * 2);
  unsigned short* parts = (unsigned short*)hbuf;

  TcArgs ta;
  ta.src[0] = Wq;  ta.dst[0] = Wqt;  ta.K[0] = 1024; ta.N[0] = 1024; ta.start[0] = 0;
  ta.src[1] = Wk;  ta.dst[1] = Wkt;  ta.K[1] = 1024; ta.N[1] = 1024; ta.start[1] = 1024;
  ta.src[2] = Wv;  ta.dst[2] = Wvt;  ta.K[2] = 1024; ta.N[2] = 1024; ta.start[2] = 2048;
  ta.src[3] = Wo;  ta.dst[3] = Wot;  ta.K[3] = 1024; ta.N[3] = 1024; ta.start[3] = 3072;
  ta.src[4] = W1;  ta.dst[4] = W1t;  ta.K[4] = 1024; ta.N[4] = 4096; ta.start[4] = 4096;
  ta.src[5] = W2;  ta.dst[5] = W2t;  ta.K[5] = 4096; ta.N[5] = 1024; ta.start[5] = 8192;
  transpose_cast6_kernel<<<12288, dim3(32, 8), 0, stream>>>(ta);

  ln_kernel<<<NROWS, 256, 0, stream>>>(x, ln1s, ln1b, hbuf);

  gemm_bt_kernel<0><<<dim3(32, 24), 256, 0, stream>>>(
      hbuf, Wqt, nullptr, nullptr, nullptr, qbuf, kbuf, (unsigned short*)vtbuf,
      1024, 1024);

  attn_kernel<<<1024, 256, 0, stream>>>(qbuf, kbuf, vtbuf, ctxbuf);

  gemm_bt_kernel<1><<<dim3(32, 8), 256, 0, stream>>>(
      ctxbuf, Wot, x1buf, bo, x, nullptr, nullptr, nullptr, 1024, 1024);

  ln_kernel<<<NROWS, 256, 0, stream>>>(x1buf, ln2s, ln2b, h2buf);

  gemm_bt_kernel<2><<<dim3(32, 32), 256, 0, stream>>>(
      h2buf, W1t, gbuf, b1, nullptr, nullptr, nullptr, nullptr, 1024, 1024);

  gemm_bt_kernel<3><<<dim3(32, 8, 4), 256, 0, stream>>>(
      gbuf, W2t, parts, nullptr, nullptr, nullptr, nullptr, nullptr, 4096, 1024);

  ffn2_reduce_kernel<<<2048, 256, 0, stream>>>(parts, b2, x1buf, out);
}

// Round 12
// 205.792 us; speedup vs baseline: 1.4266x; 1.2434x over previous
//
#include <hip/hip_runtime.h>
#include <hip/hip_bf16.h>
#include <cstdint>

#define D_DIM 1024
#define S_DIM 2048
#define B_DIM 2
#define NROWS 4096
#define H_DIM 16
#define LOG2E 1.4426950408889634f
#define QSCALE (0.125f * LOG2E)

typedef __bf16 bf16x8 __attribute__((ext_vector_type(8)));
typedef float f32x4 __attribute__((ext_vector_type(4)));
typedef unsigned short u16x8 __attribute__((ext_vector_type(8)));

#define MFMA16(a, b, c) __builtin_amdgcn_mfma_f32_16x16x32_bf16(a, b, c, 0, 0, 0)

__device__ __forceinline__ void async_cp16(const void* g, void* lds) {
  __builtin_amdgcn_global_load_lds(
      (const __attribute__((address_space(1))) void*)(uintptr_t)g,
      (__attribute__((address_space(3))) void*)(uint32_t)(uintptr_t)lds, 16, 0, 0);
}

__device__ __forceinline__ unsigned short f2bf(float f) {
  __hip_bfloat16 h = __float2bfloat16(f);
  return __builtin_bit_cast(unsigned short, h);
}

__device__ __forceinline__ float bf2f(unsigned short u) {
  return __builtin_bit_cast(float, (unsigned int)u << 16);
}

// gelu via sigmoid identity: 0.5*(1+tanh(u)) = 1/(1+exp(-2u)); exp2-space.
__device__ __forceinline__ float gelu_fast(float v) {
  float u = v * v;
  float w = v * fmaf(u, 0.044715f, 1.f);
  float e = exp2f(w * -2.3022161f);  // -2*0.79788456*log2(e)
  return v * __builtin_amdgcn_rcpf(1.f + e);
}

// ---------------- fused weight transpose+cast: 6 matrices in one launch -----
struct TcArgs {
  const float* src[6];
  __hip_bfloat16* dst[6];
  int K[6];
  int N[6];
  int start[6];
};

__global__ __launch_bounds__(256) void transpose_cast6_kernel(TcArgs a) {
  __shared__ float tile[32][33];
  int bid = blockIdx.x, mi = 0;
#pragma unroll
  for (int i = 1; i < 6; i++)
    if (bid >= a.start[i]) mi = i;
  const float* W = a.src[mi];
  __hip_bfloat16* Wt = a.dst[mi];
  int K = a.K[mi], N = a.N[mi];
  int rel = bid - a.start[mi];
  int tilesx = N >> 5;
  int shift = (N == 4096) ? 7 : 5;
  int n0 = (rel & (tilesx - 1)) * 32, k0 = (rel >> shift) * 32;
  int tx = threadIdx.x, ty = threadIdx.y;
#pragma unroll
  for (int i = 0; i < 32; i += 8)
    tile[ty + i][tx] = W[(size_t)(k0 + ty + i) * N + n0 + tx];
  __syncthreads();
#pragma unroll
  for (int i = 0; i < 32; i += 8)
    Wt[(size_t)(n0 + ty + i) * K + k0 + tx] = __float2bfloat16(tile[tx][ty + i]);
}

// ---------------- layernorm (ddof=1) f32 -> bf16 -----------------------------
__global__ __launch_bounds__(256) void ln_kernel(
    const float* __restrict__ x, const float* __restrict__ sc,
    const float* __restrict__ bi, __hip_bfloat16* __restrict__ out) {
  int row = blockIdx.x, t = threadIdx.x;
  float4 v = ((const float4*)(x + (size_t)row * D_DIM))[t];
  float s = v.x + v.y + v.z + v.w;
  float ss = v.x * v.x + v.y * v.y + v.z * v.z + v.w * v.w;
#pragma unroll
  for (int off = 32; off > 0; off >>= 1) {
    s += __shfl_xor(s, off);
    ss += __shfl_xor(ss, off);
  }
  __shared__ float red[8];
  int wid = t >> 6;
  if ((t & 63) == 0) { red[wid] = s; red[4 + wid] = ss; }
  __syncthreads();
  s = red[0] + red[1] + red[2] + red[3];
  ss = red[4] + red[5] + red[6] + red[7];
  float mean = s * (1.f / 1024.f);
  float var = (ss - 1024.f * mean * mean) * (1.f / 1023.f);
  float inv = rsqrtf(var + 1e-5f);
  float4 scv = ((const float4*)sc)[t];
  float4 biv = ((const float4*)bi)[t];
  ushort4 o;
  o.x = f2bf(scv.x * (v.x - mean) * inv + biv.x);
  o.y = f2bf(scv.y * (v.y - mean) * inv + biv.y);
  o.z = f2bf(scv.z * (v.z - mean) * inv + biv.z);
  o.w = f2bf(scv.w * (v.w - mean) * inv + biv.w);
  ((ushort4*)(out + (size_t)row * D_DIM))[t] = o;
}

// ---------------- 256x256 simple 2-phase GEMM (T3-minimum, m230: 682 TF) -----
// 512 threads = 8 waves (2m x 4n), per-wave 128x64 out. BK=64, dbuf 128 KB.
// Loop: stage(next, buf^1) BEFORE compute(buf); ONE __syncthreads per K-tile
// (compiler drains vmcnt). T2 XOR swizzle via inverse-swizzled global source.
// Bijective XCD swizzle on (x,y) grid. mi-outer compute keeps VGPR ~185.
// EPI 0: QKV (Q*=QSCALE->qb, K->kb, V transposed -> vt[b,h,d,s], seg=col>>10)
// EPI 1: gelu_fast(v+bias) -> bf16, N=4096 (FFN1)
template <int EPI>
__global__ __launch_bounds__(512) void gemm256_2ph_kernel(
    const __hip_bfloat16* __restrict__ A, const __hip_bfloat16* __restrict__ Bt,
    void* __restrict__ Cout, const float* __restrict__ bias,
    __hip_bfloat16* __restrict__ qb, __hip_bfloat16* __restrict__ kb,
    unsigned short* __restrict__ vt, int strideA, int strideB) {
  __shared__ __hip_bfloat16 As[2][256 * 64];
  __shared__ __hip_bfloat16 Bs[2][256 * 64];
  const int t = threadIdx.x;
  const int lane = t & 63, wid = t >> 6;
  const int ql = lane & 15, g = lane >> 4;
  const int wr = wid >> 2, wc = wid & 3;
  // bijective XCD swizzle (nwg % 8 == 0 for all users)
  const int nbx = gridDim.x;
  const int nwg = nbx * gridDim.y;
  const int lin = blockIdx.y * nbx + blockIdx.x;
  const int cpx = nwg >> 3;
  const int u = (lin & 7) * cpx + (lin >> 3);
  const int m0 = (u % nbx) * 256, n0 = (u / nbx) * 256;
  const int sw = (ql & 7) << 4;

  // staging: thread t covers rows (p*64 + t>>3), p=0..3; 16B chunk t&7,
  // inverse-swizzled source so linear LDS dst + swizzled reads match.
  const int srow = t >> 3;
  const int sc16 = (((t & 7) ^ (srow & 7)) << 4);
  const __hip_bfloat16* aB = A + (size_t)(m0 + srow) * strideA + (sc16 >> 1);
  const __hip_bfloat16* bB = Bt + (size_t)(n0 + srow) * strideB + (sc16 >> 1);
  const uint32_t ldsT = (uint32_t)(t * 16);

  auto stage = [&](int buf, int kt) {
#pragma unroll
    for (int p = 0; p < 4; p++)
      async_cp16(aB + (size_t)(p * 64) * strideA + kt * 64,
                 (char*)&As[buf][0] + p * 8192 + ldsT);
#pragma unroll
    for (int p = 0; p < 4; p++)
      async_cp16(bB + (size_t)(p * 64) * strideB + kt * 64,
                 (char*)&Bs[buf][0] + p * 8192 + ldsT);
  };

  f32x4 acc[8][4] = {};

  auto compute = [&](int buf) {
    // B frags for this wave's 64-col slice: 4 ni x 2 kk (32 VGPR), cached.
    bf16x8 bR[4][2];
    const char* bbase = (const char*)&Bs[buf][0] + (wc * 64 + ql) * 128;
#pragma unroll
    for (int ni = 0; ni < 4; ni++)
#pragma unroll
      for (int kk = 0; kk < 2; kk++)
        bR[ni][kk] = *(const bf16x8*)(bbase + ni * 2048 + ((kk * 64 + g * 16) ^ sw));
    const char* abase = (const char*)&As[buf][0] + (wr * 128 + ql) * 128;
#pragma unroll
    for (int mi = 0; mi < 8; mi++) {
      bf16x8 a0 = *(const bf16x8*)(abase + mi * 2048 + ((g * 16) ^ sw));
      bf16x8 a1 = *(const bf16x8*)(abase + mi * 2048 + ((64 + g * 16) ^ sw));
#pragma unroll
      for (int ni = 0; ni < 4; ni++) {
        f32x4 c = acc[mi][ni];
        c = MFMA16(a0, bR[ni][0], c);
        c = MFMA16(a1, bR[ni][1], c);
        acc[mi][ni] = c;
      }
    }
  };

  stage(0, 0);
  __syncthreads();
  int cur = 0;
  for (int kt = 0; kt < 15; ++kt) {
    stage(cur ^ 1, kt + 1);  // issue next-tile loads BEFORE compute
    compute(cur);
    __syncthreads();
    cur ^= 1;
  }
  compute(cur);

  // ---- epilogue: row = m0+wr*128+mi*16+g*4 (+rr), col = n0+wc*64+ni*16+ql
#pragma unroll
  for (int mi = 0; mi < 8; mi++) {
    const int row0 = m0 + wr * 128 + mi * 16 + (g << 2);
#pragma unroll
    for (int ni = 0; ni < 4; ni++) {
      const int col = n0 + wc * 64 + ni * 16 + ql;
      const f32x4 c = acc[mi][ni];
      if (EPI == 0) {
        const int seg = col >> 10;
        const int c1k = col & 1023;
        if (seg < 2) {
          __hip_bfloat16* Ob = seg == 0 ? qb : kb;
          const float sc = seg == 0 ? QSCALE : 1.f;
#pragma unroll
          for (int rr = 0; rr < 4; rr++)
            Ob[(size_t)(row0 + rr) * 1024 + c1k] = __float2bfloat16(c[rr] * sc);
        } else {
          const int h = c1k >> 6, dh = c1k & 63;
          const int bb = row0 >> 11, s0 = row0 & 2047;
          ushort4 pk;
          pk.x = f2bf(c[0]); pk.y = f2bf(c[1]); pk.z = f2bf(c[2]); pk.w = f2bf(c[3]);
          *(ushort4*)(vt + (((size_t)(bb * 16 + h) * 64 + dh) << 11) + s0) = pk;
        }
      } else {
        const float bv = bias[col];
#pragma unroll
        for (int rr = 0; rr < 4; rr++)
          ((__hip_bfloat16*)Cout)[(size_t)(row0 + rr) * 4096 + col] =
              __float2bfloat16(gelu_fast(c[rr] + bv));
      }
    }
  }
}

// ---------------- 128x128 GEMM (R9 structure): Wo + FFN2 split-K -------------
// BK=64, 2-region deep K-tiles, 64KB LDS, 2 blocks/CU. EPI 2: bf16 partial,
// EPI 3: f32 + bias + resid.
#define WBAR __builtin_amdgcn_s_barrier()
#define SB0 __builtin_amdgcn_sched_barrier(0)
#define LGKM0 { asm volatile("s_waitcnt lgkmcnt(0)" ::: "memory"); SB0; }
#define VMW(n) asm volatile("s_waitcnt vmcnt(" #n ")" ::: "memory")

template <int EPI>
__global__ __launch_bounds__(256) void gemm128_kernel(
    const __hip_bfloat16* __restrict__ A, const __hip_bfloat16* __restrict__ Bt,
    void* __restrict__ Cout, const float* __restrict__ bias,
    const float* __restrict__ resid, int strideA, int strideB) {
  __shared__ char lds[65536];
  const int t = threadIdx.x;
  const int lane = t & 63, wid = t >> 6;
  const int ql = lane & 15, g = lane >> 4;
  const int wr = wid >> 1, wc = wid & 1;
  const int nbm = gridDim.x, nby = gridDim.y;
  const int lin = blockIdx.y * nbm + blockIdx.x;
  const int q8 = (nbm * nby) >> 3;
  const int u = (lin & 7) * q8 + (lin >> 3);
  const int gi = u >> 5, wi = u & 31;
  const int gpc = nbm >> 2;
  const int gcol = gi / gpc, grow = gi % gpc;
  const int m0 = (grow * 4 + (wi >> 3)) * 128;
  const int n0 = (gcol * 8 + (wi & 7)) * 128;
  const int koff = blockIdx.z * 1024;
  const int sw = (ql & 7) << 4;

  const int srow = t >> 3;
  const int sc16 = (((t & 7) ^ (srow & 7)) << 4);
  const __hip_bfloat16* aB = A + (size_t)(m0 + srow) * strideA + koff + (sc16 >> 1);
  const __hip_bfloat16* bB = Bt + (size_t)(n0 + srow) * strideB + koff + (sc16 >> 1);
  const uint32_t ldsT = (uint32_t)(t * 16);

  auto stg4 = [&](int kt, int s) {
#pragma unroll
    for (int p = 0; p < 4; p++)
      async_cp16(aB + (size_t)(p * 32) * strideA + kt * 64,
                 lds + s * 16384 + p * 4096 + ldsT);
#pragma unroll
    for (int p = 0; p < 4; p++)
      async_cp16(bB + (size_t)(p * 32) * strideB + kt * 64,
                 lds + 32768 + s * 16384 + p * 4096 + ldsT);
  };

  bf16x8 aR[4][2], bR[4][2];
  f32x4 acc[4][4] = {};

  auto ldA = [&](int s) {
    const char* base = lds + s * 16384 + (wr * 64 + ql) * 128;
#pragma unroll
    for (int mi = 0; mi < 4; mi++)
#pragma unroll
      for (int kk = 0; kk < 2; kk++)
        aR[mi][kk] = *(const bf16x8*)(base + mi * 2048 + ((kk * 64 + g * 16) ^ sw));
  };
  auto ldB = [&](int s, int nh) {
    const char* base = lds + 32768 + s * 16384 + (wc * 64 + ql) * 128;
#pragma unroll
    for (int ni = 0; ni < 2; ni++)
#pragma unroll
      for (int kk = 0; kk < 2; kk++)
        bR[nh * 2 + ni][kk] =
            *(const bf16x8*)(base + (nh * 2 + ni) * 2048 + ((kk * 64 + g * 16) ^ sw));
  };
  auto mma = [&](int nh) {
    __builtin_amdgcn_s_setprio(1);
#pragma unroll
    for (int mi = 0; mi < 4; mi++)
#pragma unroll
      for (int ni = 0; ni < 2; ni++) {
        f32x4 c = acc[mi][nh * 2 + ni];
        c = MFMA16(aR[mi][0], bR[nh * 2 + ni][0], c);
        c = MFMA16(aR[mi][1], bR[nh * 2 + ni][1], c);
        acc[mi][nh * 2 + ni] = c;
      }
    __builtin_amdgcn_s_setprio(0);
  };

  stg4(0, 0); stg4(1, 1);
  VMW(8); WBAR;

#pragma unroll 1
  for (int kt = 0; kt < 14; ++kt) {
    const int s = kt & 1;
    ldA(s); ldB(s, 0);
    LGKM0; mma(0);
    ldB(s, 1);
    LGKM0; WBAR; SB0;
    stg4(kt + 2, s);
    mma(1);
    VMW(8); WBAR;
  }
  ldA(0); ldB(0, 0);
  LGKM0; mma(0);
  ldB(0, 1);
  LGKM0; WBAR;
  mma(1);
  VMW(0); WBAR;
  ldA(1); ldB(1, 0);
  LGKM0; mma(0);
  ldB(1, 1);
  LGKM0; mma(1);

#pragma unroll
  for (int mi = 0; mi < 4; mi++) {
    const int row0 = m0 + wr * 64 + mi * 16 + (g << 2);
#pragma unroll
    for (int ni = 0; ni < 4; ni++) {
      const int col = n0 + wc * 64 + ni * 16 + ql;
      const f32x4 c = acc[mi][ni];
      if (EPI == 2) {
        unsigned short* Cp = (unsigned short*)Cout + (size_t)blockIdx.z * NROWS * 1024;
#pragma unroll
        for (int rr = 0; rr < 4; rr++)
          Cp[(size_t)(row0 + rr) * 1024 + col] = f2bf(c[rr]);
      } else {
        const float bv = bias[col];
#pragma unroll
        for (int rr = 0; rr < 4; rr++)
          ((float*)Cout)[(size_t)(row0 + rr) * 1024 + col] =
              c[rr] + bv + resid[(size_t)(row0 + rr) * 1024 + col];
      }
    }
  }
}

// ---------------- split-K reduce + bias + residual (f32 out) -----------------
__global__ __launch_bounds__(256) void ffn2_reduce_kernel(
    const unsigned short* __restrict__ parts, const float* __restrict__ bias,
    const float* __restrict__ resid, float* __restrict__ out) {
  const size_t i = ((size_t)blockIdx.x * 256 + threadIdx.x) * 8;
  const int col = (int)(i & 1023);
  float a[8];
  float4 r0 = *(const float4*)(resid + i);
  float4 r1 = *(const float4*)(resid + i + 4);
  float4 b0 = *(const float4*)(bias + col);
  float4 b1 = *(const float4*)(bias + col + 4);
  a[0] = r0.x + b0.x; a[1] = r0.y + b0.y; a[2] = r0.z + b0.z; a[3] = r0.w + b0.w;
  a[4] = r1.x + b1.x; a[5] = r1.y + b1.y; a[6] = r1.z + b1.z; a[7] = r1.w + b1.w;
#pragma unroll
  for (int c = 0; c < 4; c++) {
    u16x8 p = *(const u16x8*)(parts + (size_t)c * ((size_t)NROWS * 1024) + i);
#pragma unroll
    for (int j = 0; j < 8; j++) a[j] += bf2f(p[j]);
  }
  float4 o0 = {a[0], a[1], a[2], a[3]};
  float4 o1 = {a[4], a[5], a[6], a[7]};
  *(float4*)(out + i) = o0;
  *(float4*)(out + i + 4) = o1;
}

// ---------------- causal flash attention, LDS-staged K/V (unchanged) ---------
__global__ __launch_bounds__(256) void attn_kernel(
    const __hip_bfloat16* __restrict__ Q, const __hip_bfloat16* __restrict__ Kb,
    const __hip_bfloat16* __restrict__ Vt, __hip_bfloat16* __restrict__ ctx) {
  __shared__ unsigned short Ks[2][64 * 64];
  __shared__ unsigned short Vs[2][64 * 64];
  __shared__ alignas(16) unsigned short Ps[4][16 * 64];
  const int t = threadIdx.x;
  const int lane = t & 63, wid = t >> 6;
  const int ql = lane & 15, g = lane >> 4;
  const int bid = blockIdx.x;
  const int r4 = bid >> 8, k8 = (bid >> 5) & 7, bh = bid & 31;
  const int qt = (r4 == 0) ? 31 - k8 : (r4 == 1) ? 16 + k8 : (r4 == 2) ? 15 - k8 : k8;
  const int b = bh >> 4, hh = bh & 15;
  const int wq0 = qt * 64 + wid * 16;
  const __hip_bfloat16* qp = Q + (size_t)b * S_DIM * D_DIM + hh * 64;
  const __hip_bfloat16* kp = Kb + (size_t)b * S_DIM * D_DIM + hh * 64;
  const __hip_bfloat16* vp = Vt + (size_t)bh * 64 * S_DIM;
  const int kvend = qt * 64 + 64;
  const int swz = (ql & 7) << 4;
  const f32x4 z4 = {0.f, 0.f, 0.f, 0.f};

  auto stageKV = [&](int buf, int kv0) {
    const int sub = lane >> 3, c = lane & 7;
#pragma unroll
    for (int i = 0; i < 2; i++) {
      const int row = wid * 16 + i * 8 + sub;
      const int cs = (c ^ (row & 7)) * 8;
      async_cp16(kp + (size_t)(kv0 + row) * D_DIM + cs,
                 (char*)&Ks[buf][0] + (wid * 16 + i * 8) * 128);
      async_cp16(vp + (size_t)row * S_DIM + kv0 + cs,
                 (char*)&Vs[buf][0] + (wid * 16 + i * 8) * 128);
    }
  };

  bf16x8 qf[2];
#pragma unroll
  for (int hf = 0; hf < 2; hf++)
    qf[hf] = *(const bf16x8*)(qp + (size_t)(wq0 + ql) * D_DIM + hf * 32 + g * 8);

  float m = -3.0e38f, lsum = 0.f;
  f32x4 acc[4] = {};
  unsigned short* Pw = Ps[wid];

  stageKV(0, 0);
  __syncthreads();
  int cur = 0;
  for (int kv0 = 0; kv0 < kvend; kv0 += 64) {
    if (kv0 + 64 < kvend) stageKV(cur ^ 1, kv0 + 64);

    if (kv0 <= wq0 + 15) {
      const char* Kt = (const char*)&Ks[cur][0];
      f32x4 st[4];
#pragma unroll
      for (int ks = 0; ks < 4; ks++) {
        bf16x8 k0 = *(const bf16x8*)(Kt + (ks * 16 + ql) * 128 + ((g * 16) ^ swz));
        bf16x8 k1 = *(const bf16x8*)(Kt + (ks * 16 + ql) * 128 + (((4 + g) * 16) ^ swz));
        st[ks] = MFMA16(k1, qf[1], MFMA16(k0, qf[0], z4));
      }
      if (kv0 + 63 > wq0) {
#pragma unroll
        for (int ks = 0; ks < 4; ks++)
#pragma unroll
          for (int r = 0; r < 4; r++)
            if (kv0 + ks * 16 + 4 * g + r > wq0 + ql) st[ks][r] = -3.0e38f;
      }
      float tm = -3.0e38f;
#pragma unroll
      for (int ks = 0; ks < 4; ks++)
#pragma unroll
        for (int r = 0; r < 4; r++) tm = fmaxf(tm, st[ks][r]);
      tm = fmaxf(tm, __shfl_xor(tm, 16));
      tm = fmaxf(tm, __shfl_xor(tm, 32));
      if (!__all(tm <= m + 8.f)) {
        const float mn = fmaxf(m, tm);
        const float alpha = exp2f(m - mn);
        lsum *= alpha;
#pragma unroll
        for (int db = 0; db < 4; db++) acc[db] *= alpha;
        m = mn;
      }
      float psum = 0.f;
#pragma unroll
      for (int ks = 0; ks < 4; ks++) {
        float p0 = exp2f(st[ks][0] - m), p1 = exp2f(st[ks][1] - m);
        float p2 = exp2f(st[ks][2] - m), p3 = exp2f(st[ks][3] - m);
        psum += (p0 + p1) + (p2 + p3);
        ushort4 pk;
        pk.x = f2bf(p0); pk.y = f2bf(p1); pk.z = f2bf(p2); pk.w = f2bf(p3);
        *(ushort4*)((char*)Pw + ql * 128 + ((ks * 32 + 8 * g) ^ swz)) = pk;
      }
      psum += __shfl_xor(psum, 16);
      psum += __shfl_xor(psum, 32);
      lsum += psum;

      const char* Vtl = (const char*)&Vs[cur][0];
#pragma unroll
      for (int ksl = 0; ksl < 2; ksl++) {
        bf16x8 pb = *(const bf16x8*)((const char*)Pw + ql * 128 + ((ksl * 64 + 16 * g) ^ swz));
#pragma unroll
        for (int db = 0; db < 4; db++) {
          bf16x8 va = *(const bf16x8*)(Vtl + (db * 16 + ql) * 128 + (((ksl * 4 + g) * 16) ^ swz));
          acc[db] = MFMA16(va, pb, acc[db]);
        }
      }
    }
    __syncthreads();
    cur ^= 1;
  }

  const float inv = 1.f / lsum;
  unsigned short* cp = (unsigned short*)ctx + (size_t)(b * S_DIM + wq0 + ql) * D_DIM + hh * 64;
#pragma unroll
  for (int db = 0; db < 4; db++)
#pragma unroll
    for (int i = 0; i < 2; i++) {
      unsigned int lo = f2bf(acc[db][2 * i] * inv);
      unsigned int hi = f2bf(acc[db][2 * i + 1] * inv);
      *(unsigned int*)(cp + db * 16 + 4 * g + 2 * i) = lo | (hi << 16);
    }
}

// ---------------- orchestration ----------------------------------------------
extern "C" void kernel_launch(void* const* d_in, const int* in_sizes, int n_in,
                              void* d_out, int out_size, void* d_ws, size_t ws_size,
                              hipStream_t stream) {
  const float* x = (const float*)d_in[0];
  const float* Wq = (const float*)d_in[1];
  const float* Wk = (const float*)d_in[2];
  const float* Wv = (const float*)d_in[3];
  const float* Wo = (const float*)d_in[4];
  const float* bo = (const float*)d_in[5];
  const float* W1 = (const float*)d_in[6];
  const float* b1 = (const float*)d_in[7];
  const float* W2 = (const float*)d_in[8];
  const float* b2 = (const float*)d_in[9];
  const float* ln1s = (const float*)d_in[10];
  const float* ln1b = (const float*)d_in[11];
  const float* ln2s = (const float*)d_in[12];
  const float* ln2b = (const float*)d_in[13];
  float* out = (float*)d_out;

  char* p = (char*)d_ws;
  auto take = [&](size_t n) { char* r = p; p += (n + 255) & ~(size_t)255; return r; };
  // Wqt/Wkt/Wvt contiguous -> one [3072][1024] B^T for the fused QKV GEMM.
  __hip_bfloat16* Wqt = (__hip_bfloat16*)take((size_t)1024 * 1024 * 2);
  __hip_bfloat16* Wkt = (__hip_bfloat16*)take((size_t)1024 * 1024 * 2);
  __hip_bfloat16* Wvt = (__hip_bfloat16*)take((size_t)1024 * 1024 * 2);
  __hip_bfloat16* Wot = (__hip_bfloat16*)take((size_t)1024 * 1024 * 2);
  __hip_bfloat16* W1t = (__hip_bfloat16*)take((size_t)4096 * 1024 * 2);
  __hip_bfloat16* W2t = (__hip_bfloat16*)take((size_t)4096 * 1024 * 2);
  __hip_bfloat16* hbuf = (__hip_bfloat16*)take((size_t)NROWS * 1024 * 2);
  __hip_bfloat16* qbuf = (__hip_bfloat16*)take((size_t)NROWS * 1024 * 2);
  __hip_bfloat16* kbuf = (__hip_bfloat16*)take((size_t)NROWS * 1024 * 2);
  __hip_bfloat16* vtbuf = (__hip_bfloat16*)take((size_t)NROWS * 1024 * 2);
  __hip_bfloat16* ctxbuf = (__hip_bfloat16*)take((size_t)NROWS * 1024 * 2);
  float* x1buf = (float*)take((size_t)NROWS * 1024 * 4);
  __hip_bfloat16* h2buf = (__hip_bfloat16*)take((size_t)NROWS * 1024 * 2);
  __hip_bfloat16* gbuf = (__hip_bfloat16*)take((size_t)NROWS * 4096 * 2);
  unsigned short* parts = (unsigned short*)hbuf;

  TcArgs ta;
  ta.src[0] = Wq;  ta.dst[0] = Wqt;  ta.K[0] = 1024; ta.N[0] = 1024; ta.start[0] = 0;
  ta.src[1] = Wk;  ta.dst[1] = Wkt;  ta.K[1] = 1024; ta.N[1] = 1024; ta.start[1] = 1024;
  ta.src[2] = Wv;  ta.dst[2] = Wvt;  ta.K[2] = 1024; ta.N[2] = 1024; ta.start[2] = 2048;
  ta.src[3] = Wo;  ta.dst[3] = Wot;  ta.K[3] = 1024; ta.N[3] = 1024; ta.start[3] = 3072;
  ta.src[4] = W1;  ta.dst[4] = W1t;  ta.K[4] = 1024; ta.N[4] = 4096; ta.start[4] = 4096;
  ta.src[5] = W2;  ta.dst[5] = W2t;  ta.K[5] = 4096; ta.N[5] = 1024; ta.start[5] = 8192;
  transpose_cast6_kernel<<<12288, dim3(32, 8), 0, stream>>>(ta);

  ln_kernel<<<NROWS, 256, 0, stream>>>(x, ln1s, ln1b, hbuf);

  gemm256_2ph_kernel<0><<<dim3(16, 12), 512, 0, stream>>>(
      hbuf, Wqt, nullptr, nullptr, qbuf, kbuf, (unsigned short*)vtbuf, 1024, 1024);

  attn_kernel<<<1024, 256, 0, stream>>>(qbuf, kbuf, vtbuf, ctxbuf);

  gemm128_kernel<3><<<dim3(32, 8), 256, 0, stream>>>(
      ctxbuf, Wot, x1buf, bo, x, 1024, 1024);

  ln_kernel<<<NROWS, 256, 0, stream>>>(x1buf, ln2s, ln2b, h2buf);

  gemm256_2ph_kernel<1><<<dim3(16, 16), 512, 0, stream>>>(
      h2buf, W1t, gbuf, b1, nullptr, nullptr, nullptr, 1024, 1024);

  gemm128_kernel<2><<<dim3(32, 8, 4), 256, 0, stream>>>(
      gbuf, W2t, parts, nullptr, nullptr, 4096, 4096);

  ffn2_reduce_kernel<<<2048, 256, 0, stream>>>(parts, b2, x1buf, out);
}

// Round 13
// 202.346 us; speedup vs baseline: 1.4509x; 1.0170x over previous
//
#include <hip/hip_runtime.h>
#include <hip/hip_bf16.h>
#include <cstdint>

#define D_DIM 1024
#define S_DIM 2048
#define B_DIM 2
#define NROWS 4096
#define H_DIM 16
#define LOG2E 1.4426950408889634f
#define QSCALE (0.125f * LOG2E)

typedef __bf16 bf16x8 __attribute__((ext_vector_type(8)));
typedef float f32x4 __attribute__((ext_vector_type(4)));
typedef unsigned short u16x8 __attribute__((ext_vector_type(8)));

#define MFMA16(a, b, c) __builtin_amdgcn_mfma_f32_16x16x32_bf16(a, b, c, 0, 0, 0)
#define WBAR __builtin_amdgcn_s_barrier()
#define SB0 __builtin_amdgcn_sched_barrier(0)
// rule #18: inline-asm lgkmcnt(0) must be followed by sched_barrier(0)
#define LGKM0 { asm volatile("s_waitcnt lgkmcnt(0)" ::: "memory"); SB0; }
#define VMW(n) asm volatile("s_waitcnt vmcnt(" #n ")" ::: "memory")

__device__ __forceinline__ void async_cp16(const void* g, void* lds) {
  __builtin_amdgcn_global_load_lds(
      (const __attribute__((address_space(1))) void*)(uintptr_t)g,
      (__attribute__((address_space(3))) void*)(uint32_t)(uintptr_t)lds, 16, 0, 0);
}

__device__ __forceinline__ unsigned short f2bf(float f) {
  __hip_bfloat16 h = __float2bfloat16(f);
  return __builtin_bit_cast(unsigned short, h);
}

__device__ __forceinline__ float bf2f(unsigned short u) {
  return __builtin_bit_cast(float, (unsigned int)u << 16);
}

// gelu via sigmoid identity: 0.5*(1+tanh(u)) = 1/(1+exp(-2u)); exp2-space.
__device__ __forceinline__ float gelu_fast(float v) {
  float u = v * v;
  float w = v * fmaf(u, 0.044715f, 1.f);
  float e = exp2f(w * -2.3022161f);  // -2*0.79788456*log2(e)
  return v * __builtin_amdgcn_rcpf(1.f + e);
}

// ---------------- fused weight transpose+cast: 6 matrices in one launch -----
struct TcArgs {
  const float* src[6];
  __hip_bfloat16* dst[6];
  int K[6];
  int N[6];
  int start[6];
};

__global__ __launch_bounds__(256) void transpose_cast6_kernel(TcArgs a) {
  __shared__ float tile[32][33];
  int bid = blockIdx.x, mi = 0;
#pragma unroll
  for (int i = 1; i < 6; i++)
    if (bid >= a.start[i]) mi = i;
  const float* W = a.src[mi];
  __hip_bfloat16* Wt = a.dst[mi];
  int K = a.K[mi], N = a.N[mi];
  int rel = bid - a.start[mi];
  int tilesx = N >> 5;
  int shift = (N == 4096) ? 7 : 5;
  int n0 = (rel & (tilesx - 1)) * 32, k0 = (rel >> shift) * 32;
  int tx = threadIdx.x, ty = threadIdx.y;
#pragma unroll
  for (int i = 0; i < 32; i += 8)
    tile[ty + i][tx] = W[(size_t)(k0 + ty + i) * N + n0 + tx];
  __syncthreads();
#pragma unroll
  for (int i = 0; i < 32; i += 8)
    Wt[(size_t)(n0 + ty + i) * K + k0 + tx] = __float2bfloat16(tile[tx][ty + i]);
}

// ---------------- layernorm (ddof=1) f32 -> bf16 -----------------------------
__global__ __launch_bounds__(256) void ln_kernel(
    const float* __restrict__ x, const float* __restrict__ sc,
    const float* __restrict__ bi, __hip_bfloat16* __restrict__ out) {
  int row = blockIdx.x, t = threadIdx.x;
  float4 v = ((const float4*)(x + (size_t)row * D_DIM))[t];
  float s = v.x + v.y + v.z + v.w;
  float ss = v.x * v.x + v.y * v.y + v.z * v.z + v.w * v.w;
#pragma unroll
  for (int off = 32; off > 0; off >>= 1) {
    s += __shfl_xor(s, off);
    ss += __shfl_xor(ss, off);
  }
  __shared__ float red[8];
  int wid = t >> 6;
  if ((t & 63) == 0) { red[wid] = s; red[4 + wid] = ss; }
  __syncthreads();
  s = red[0] + red[1] + red[2] + red[3];
  ss = red[4] + red[5] + red[6] + red[7];
  float mean = s * (1.f / 1024.f);
  float var = (ss - 1024.f * mean * mean) * (1.f / 1023.f);
  float inv = rsqrtf(var + 1e-5f);
  float4 scv = ((const float4*)sc)[t];
  float4 biv = ((const float4*)bi)[t];
  ushort4 o;
  o.x = f2bf(scv.x * (v.x - mean) * inv + biv.x);
  o.y = f2bf(scv.y * (v.y - mean) * inv + biv.y);
  o.z = f2bf(scv.z * (v.z - mean) * inv + biv.z);
  o.w = f2bf(scv.w * (v.w - mean) * inv + biv.w);
  ((ushort4*)(out + (size_t)row * D_DIM))[t] = o;
}

// ---------------- 128x128 GEMM (R9 structure), runtime K-depth ---------------
// 256 threads (4 waves, 2x2), per-wave 64x64. BK=64, nkt K-tiles (even), LDS
// 64KB dbuf -> 2 blocks/CU. Per kt: {ldA+ldB0; lgkm0; mma0; ldB1; lgkm0; BAR;
// stg4(kt+2); mma1; VMW(8); BAR}. Peeled last two kt drain VM 0.
// EPI 0: QKV (col<2048: Q*=QSCALE->qb / K->kb; else V transposed vt[b,h,d,s])
// EPI 1: gelu_fast(v+bias) -> bf16, stride 4096 (FFN1)
// EPI 2: f32 + bias + resid, stride 1024 (Wo, FFN2)
template <int EPI>
__global__ __launch_bounds__(256) void gemm128_kernel(
    const __hip_bfloat16* __restrict__ A, const __hip_bfloat16* __restrict__ Bt,
    void* __restrict__ Cout, const float* __restrict__ bias,
    const float* __restrict__ resid, __hip_bfloat16* __restrict__ qb,
    __hip_bfloat16* __restrict__ kb, unsigned short* __restrict__ vt,
    int strideA, int strideB, int nkt) {
  __shared__ char lds[65536];
  const int t = threadIdx.x;
  const int lane = t & 63, wid = t >> 6;
  const int ql = lane & 15, g = lane >> 4;
  const int wr = wid >> 1, wc = wid & 1;

  // grid decode: bijective XCD chunk -> 4m x 8n groups, column-major groups
  const int nbm = gridDim.x, nby = gridDim.y;
  const int lin = blockIdx.y * nbm + blockIdx.x;
  const int q8 = (nbm * nby) >> 3;
  const int u = (lin & 7) * q8 + (lin >> 3);
  const int gi = u >> 5, wi = u & 31;
  const int gpc = nbm >> 2;
  const int gcol = gi / gpc, grow = gi % gpc;
  const int m0 = (grow * 4 + (wi >> 3)) * 128;
  const int n0 = (gcol * 8 + (wi & 7)) * 128;
  const int sw = (ql & 7) << 4;

  const int srow = t >> 3;
  const int sc16 = (((t & 7) ^ (srow & 7)) << 4);  // inverse-swizzled src byte
  const __hip_bfloat16* aB = A + (size_t)(m0 + srow) * strideA + (sc16 >> 1);
  const __hip_bfloat16* bB = Bt + (size_t)(n0 + srow) * strideB + (sc16 >> 1);
  const uint32_t ldsT = (uint32_t)(t * 16);

  auto stg4 = [&](int kt, int s) {
#pragma unroll
    for (int p = 0; p < 4; p++)
      async_cp16(aB + (size_t)(p * 32) * strideA + kt * 64,
                 lds + s * 16384 + p * 4096 + ldsT);
#pragma unroll
    for (int p = 0; p < 4; p++)
      async_cp16(bB + (size_t)(p * 32) * strideB + kt * 64,
                 lds + 32768 + s * 16384 + p * 4096 + ldsT);
  };

  bf16x8 aR[4][2], bR[4][2];
  f32x4 acc[4][4] = {};

  auto ldA = [&](int s) {
    const char* base = lds + s * 16384 + (wr * 64 + ql) * 128;
#pragma unroll
    for (int mi = 0; mi < 4; mi++)
#pragma unroll
      for (int kk = 0; kk < 2; kk++)
        aR[mi][kk] = *(const bf16x8*)(base + mi * 2048 + ((kk * 64 + g * 16) ^ sw));
  };
  auto ldB = [&](int s, int nh) {
    const char* base = lds + 32768 + s * 16384 + (wc * 64 + ql) * 128;
#pragma unroll
    for (int ni = 0; ni < 2; ni++)
#pragma unroll
      for (int kk = 0; kk < 2; kk++)
        bR[nh * 2 + ni][kk] =
            *(const bf16x8*)(base + (nh * 2 + ni) * 2048 + ((kk * 64 + g * 16) ^ sw));
  };
  auto mma = [&](int nh) {
    __builtin_amdgcn_s_setprio(1);
#pragma unroll
    for (int mi = 0; mi < 4; mi++)
#pragma unroll
      for (int ni = 0; ni < 2; ni++) {
        f32x4 c = acc[mi][nh * 2 + ni];
        c = MFMA16(aR[mi][0], bR[nh * 2 + ni][0], c);
        c = MFMA16(aR[mi][1], bR[nh * 2 + ni][1], c);
        acc[mi][nh * 2 + ni] = c;
      }
    __builtin_amdgcn_s_setprio(0);
  };

  // prologue: kt0 -> slot0, kt1 -> slot1 (16 loads); VMW(8) -> kt0 resident.
  stg4(0, 0); stg4(1, 1);
  VMW(8); WBAR;

#pragma unroll 1
  for (int kt = 0; kt < nkt - 2; ++kt) {
    const int s = kt & 1;
    ldA(s); ldB(s, 0);
    LGKM0; mma(0);
    ldB(s, 1);
    LGKM0; WBAR; SB0;   // all waves' slot-s reads done -> slot s reusable
    stg4(kt + 2, s);    // 8 gloads, 2 kt ahead
    mma(1);
    VMW(8); WBAR;       // retire kt+1's loads
  }
  // kt = nkt-2 (slot 0, nkt even): no stage; drain last kt's loads.
  ldA(0); ldB(0, 0);
  LGKM0; mma(0);
  ldB(0, 1);
  LGKM0; WBAR;
  mma(1);
  VMW(0); WBAR;
  // kt = nkt-1 (slot 1): pure compute.
  ldA(1); ldB(1, 0);
  LGKM0; mma(0);
  ldB(1, 1);
  LGKM0; mma(1);

  // ---- epilogue: row = m0 + wr*64 + mi*16 + g*4 (+rr), col = n0 + wc*64 + ni*16 + ql
#pragma unroll
  for (int mi = 0; mi < 4; mi++) {
    const int row0 = m0 + wr * 64 + mi * 16 + (g << 2);
#pragma unroll
    for (int ni = 0; ni < 4; ni++) {
      const int col = n0 + wc * 64 + ni * 16 + ql;
      const f32x4 c = acc[mi][ni];
      if (EPI == 0) {
        const int seg = col >> 10;
        const int c1k = col & 1023;
        if (seg < 2) {
          __hip_bfloat16* Ob = seg == 0 ? qb : kb;
          const float sc = seg == 0 ? QSCALE : 1.f;
#pragma unroll
          for (int rr = 0; rr < 4; rr++)
            Ob[(size_t)(row0 + rr) * 1024 + c1k] = __float2bfloat16(c[rr] * sc);
        } else {
          const int h = c1k >> 6, dh = c1k & 63;
          const int bb = row0 >> 11, s0 = row0 & 2047;
          ushort4 pk;
          pk.x = f2bf(c[0]); pk.y = f2bf(c[1]); pk.z = f2bf(c[2]); pk.w = f2bf(c[3]);
          *(ushort4*)(vt + (((size_t)(bb * 16 + h) * 64 + dh) << 11) + s0) = pk;
        }
      } else if (EPI == 1) {
        const float bv = bias[col];
#pragma unroll
        for (int rr = 0; rr < 4; rr++)
          ((__hip_bfloat16*)Cout)[(size_t)(row0 + rr) * 4096 + col] =
              __float2bfloat16(gelu_fast(c[rr] + bv));
      } else {
        const float bv = bias[col];
#pragma unroll
        for (int rr = 0; rr < 4; rr++)
          ((float*)Cout)[(size_t)(row0 + rr) * 1024 + col] =
              c[rr] + bv + resid[(size_t)(row0 + rr) * 1024 + col];
      }
    }
  }
}

// ---------------- causal flash attention, LDS-staged K/V (unchanged) ---------
__global__ __launch_bounds__(256) void attn_kernel(
    const __hip_bfloat16* __restrict__ Q, const __hip_bfloat16* __restrict__ Kb,
    const __hip_bfloat16* __restrict__ Vt, __hip_bfloat16* __restrict__ ctx) {
  __shared__ unsigned short Ks[2][64 * 64];
  __shared__ unsigned short Vs[2][64 * 64];
  __shared__ alignas(16) unsigned short Ps[4][16 * 64];
  const int t = threadIdx.x;
  const int lane = t & 63, wid = t >> 6;
  const int ql = lane & 15, g = lane >> 4;
  const int bid = blockIdx.x;
  const int r4 = bid >> 8, k8 = (bid >> 5) & 7, bh = bid & 31;
  const int qt = (r4 == 0) ? 31 - k8 : (r4 == 1) ? 16 + k8 : (r4 == 2) ? 15 - k8 : k8;
  const int b = bh >> 4, hh = bh & 15;
  const int wq0 = qt * 64 + wid * 16;
  const __hip_bfloat16* qp = Q + (size_t)b * S_DIM * D_DIM + hh * 64;
  const __hip_bfloat16* kp = Kb + (size_t)b * S_DIM * D_DIM + hh * 64;
  const __hip_bfloat16* vp = Vt + (size_t)bh * 64 * S_DIM;
  const int kvend = qt * 64 + 64;
  const int swz = (ql & 7) << 4;
  const f32x4 z4 = {0.f, 0.f, 0.f, 0.f};

  auto stageKV = [&](int buf, int kv0) {
    const int sub = lane >> 3, c = lane & 7;
#pragma unroll
    for (int i = 0; i < 2; i++) {
      const int row = wid * 16 + i * 8 + sub;
      const int cs = (c ^ (row & 7)) * 8;
      async_cp16(kp + (size_t)(kv0 + row) * D_DIM + cs,
                 (char*)&Ks[buf][0] + (wid * 16 + i * 8) * 128);
      async_cp16(vp + (size_t)row * S_DIM + kv0 + cs,
                 (char*)&Vs[buf][0] + (wid * 16 + i * 8) * 128);
    }
  };

  bf16x8 qf[2];
#pragma unroll
  for (int hf = 0; hf < 2; hf++)
    qf[hf] = *(const bf16x8*)(qp + (size_t)(wq0 + ql) * D_DIM + hf * 32 + g * 8);

  float m = -3.0e38f, lsum = 0.f;
  f32x4 acc[4] = {};
  unsigned short* Pw = Ps[wid];

  stageKV(0, 0);
  __syncthreads();
  int cur = 0;
  for (int kv0 = 0; kv0 < kvend; kv0 += 64) {
    if (kv0 + 64 < kvend) stageKV(cur ^ 1, kv0 + 64);

    if (kv0 <= wq0 + 15) {
      const char* Kt = (const char*)&Ks[cur][0];
      f32x4 st[4];
#pragma unroll
      for (int ks = 0; ks < 4; ks++) {
        bf16x8 k0 = *(const bf16x8*)(Kt + (ks * 16 + ql) * 128 + ((g * 16) ^ swz));
        bf16x8 k1 = *(const bf16x8*)(Kt + (ks * 16 + ql) * 128 + (((4 + g) * 16) ^ swz));
        st[ks] = MFMA16(k1, qf[1], MFMA16(k0, qf[0], z4));
      }
      if (kv0 + 63 > wq0) {
#pragma unroll
        for (int ks = 0; ks < 4; ks++)
#pragma unroll
          for (int r = 0; r < 4; r++)
            if (kv0 + ks * 16 + 4 * g + r > wq0 + ql) st[ks][r] = -3.0e38f;
      }
      float tm = -3.0e38f;
#pragma unroll
      for (int ks = 0; ks < 4; ks++)
#pragma unroll
        for (int r = 0; r < 4; r++) tm = fmaxf(tm, st[ks][r]);
      tm = fmaxf(tm, __shfl_xor(tm, 16));
      tm = fmaxf(tm, __shfl_xor(tm, 32));
      if (!__all(tm <= m + 8.f)) {
        const float mn = fmaxf(m, tm);
        const float alpha = exp2f(m - mn);
        lsum *= alpha;
#pragma unroll
        for (int db = 0; db < 4; db++) acc[db] *= alpha;
        m = mn;
      }
      float psum = 0.f;
#pragma unroll
      for (int ks = 0; ks < 4; ks++) {
        float p0 = exp2f(st[ks][0] - m), p1 = exp2f(st[ks][1] - m);
        float p2 = exp2f(st[ks][2] - m), p3 = exp2f(st[ks][3] - m);
        psum += (p0 + p1) + (p2 + p3);
        ushort4 pk;
        pk.x = f2bf(p0); pk.y = f2bf(p1); pk.z = f2bf(p2); pk.w = f2bf(p3);
        *(ushort4*)((char*)Pw + ql * 128 + ((ks * 32 + 8 * g) ^ swz)) = pk;
      }
      psum += __shfl_xor(psum, 16);
      psum += __shfl_xor(psum, 32);
      lsum += psum;

      const char* Vtl = (const char*)&Vs[cur][0];
#pragma unroll
      for (int ksl = 0; ksl < 2; ksl++) {
        bf16x8 pb = *(const bf16x8*)((const char*)Pw + ql * 128 + ((ksl * 64 + 16 * g) ^ swz));
#pragma unroll
        for (int db = 0; db < 4; db++) {
          bf16x8 va = *(const bf16x8*)(Vtl + (db * 16 + ql) * 128 + (((ksl * 4 + g) * 16) ^ swz));
          acc[db] = MFMA16(va, pb, acc[db]);
        }
      }
    }
    __syncthreads();
    cur ^= 1;
  }

  const float inv = 1.f / lsum;
  unsigned short* cp = (unsigned short*)ctx + (size_t)(b * S_DIM + wq0 + ql) * D_DIM + hh * 64;
#pragma unroll
  for (int db = 0; db < 4; db++)
#pragma unroll
    for (int i = 0; i < 2; i++) {
      unsigned int lo = f2bf(acc[db][2 * i] * inv);
      unsigned int hi = f2bf(acc[db][2 * i + 1] * inv);
      *(unsigned int*)(cp + db * 16 + 4 * g + 2 * i) = lo | (hi << 16);
    }
}

// ---------------- orchestration ----------------------------------------------
extern "C" void kernel_launch(void* const* d_in, const int* in_sizes, int n_in,
                              void* d_out, int out_size, void* d_ws, size_t ws_size,
                              hipStream_t stream) {
  const float* x = (const float*)d_in[0];
  const float* Wq = (const float*)d_in[1];
  const float* Wk = (const float*)d_in[2];
  const float* Wv = (const float*)d_in[3];
  const float* Wo = (const float*)d_in[4];
  const float* bo = (const float*)d_in[5];
  const float* W1 = (const float*)d_in[6];
  const float* b1 = (const float*)d_in[7];
  const float* W2 = (const float*)d_in[8];
  const float* b2 = (const float*)d_in[9];
  const float* ln1s = (const float*)d_in[10];
  const float* ln1b = (const float*)d_in[11];
  const float* ln2s = (const float*)d_in[12];
  const float* ln2b = (const float*)d_in[13];
  float* out = (float*)d_out;

  char* p = (char*)d_ws;
  auto take = [&](size_t n) { char* r = p; p += (n + 255) & ~(size_t)255; return r; };
  // Wqt/Wkt/Wvt contiguous -> one [3072][1024] B^T for the fused QKV GEMM.
  __hip_bfloat16* Wqt = (__hip_bfloat16*)take((size_t)1024 * 1024 * 2);
  __hip_bfloat16* Wkt = (__hip_bfloat16*)take((size_t)1024 * 1024 * 2);
  __hip_bfloat16* Wvt = (__hip_bfloat16*)take((size_t)1024 * 1024 * 2);
  __hip_bfloat16* Wot = (__hip_bfloat16*)take((size_t)1024 * 1024 * 2);
  __hip_bfloat16* W1t = (__hip_bfloat16*)take((size_t)4096 * 1024 * 2);
  __hip_bfloat16* W2t = (__hip_bfloat16*)take((size_t)4096 * 1024 * 2);
  __hip_bfloat16* hbuf = (__hip_bfloat16*)take((size_t)NROWS * 1024 * 2);
  __hip_bfloat16* qbuf = (__hip_bfloat16*)take((size_t)NROWS * 1024 * 2);
  __hip_bfloat16* kbuf = (__hip_bfloat16*)take((size_t)NROWS * 1024 * 2);
  __hip_bfloat16* vtbuf = (__hip_bfloat16*)take((size_t)NROWS * 1024 * 2);
  __hip_bfloat16* ctxbuf = (__hip_bfloat16*)take((size_t)NROWS * 1024 * 2);
  float* x1buf = (float*)take((size_t)NROWS * 1024 * 4);
  __hip_bfloat16* h2buf = (__hip_bfloat16*)take((size_t)NROWS * 1024 * 2);
  __hip_bfloat16* gbuf = (__hip_bfloat16*)take((size_t)NROWS * 4096 * 2);

  TcArgs ta;
  ta.src[0] = Wq;  ta.dst[0] = Wqt;  ta.K[0] = 1024; ta.N[0] = 1024; ta.start[0] = 0;
  ta.src[1] = Wk;  ta.dst[1] = Wkt;  ta.K[1] = 1024; ta.N[1] = 1024; ta.start[1] = 1024;
  ta.src[2] = Wv;  ta.dst[2] = Wvt;  ta.K[2] = 1024; ta.N[2] = 1024; ta.start[2] = 2048;
  ta.src[3] = Wo;  ta.dst[3] = Wot;  ta.K[3] = 1024; ta.N[3] = 1024; ta.start[3] = 3072;
  ta.src[4] = W1;  ta.dst[4] = W1t;  ta.K[4] = 1024; ta.N[4] = 4096; ta.start[4] = 4096;
  ta.src[5] = W2;  ta.dst[5] = W2t;  ta.K[5] = 4096; ta.N[5] = 1024; ta.start[5] = 8192;
  transpose_cast6_kernel<<<12288, dim3(32, 8), 0, stream>>>(ta);

  ln_kernel<<<NROWS, 256, 0, stream>>>(x, ln1s, ln1b, hbuf);

  gemm128_kernel<0><<<dim3(32, 24), 256, 0, stream>>>(
      hbuf, Wqt, nullptr, nullptr, nullptr, qbuf, kbuf, (unsigned short*)vtbuf,
      1024, 1024, 16);

  attn_kernel<<<1024, 256, 0, stream>>>(qbuf, kbuf, vtbuf, ctxbuf);

  gemm128_kernel<2><<<dim3(32, 8), 256, 0, stream>>>(
      ctxbuf, Wot, x1buf, bo, x, nullptr, nullptr, nullptr, 1024, 1024, 16);

  ln_kernel<<<NROWS, 256, 0, stream>>>(x1buf, ln2s, ln2b, h2buf);

  gemm128_kernel<1><<<dim3(32, 32), 256, 0, stream>>>(
      h2buf, W1t, gbuf, b1, nullptr, nullptr, nullptr, nullptr, 1024, 1024, 16);

  gemm128_kernel<2><<<dim3(32, 8), 256, 0, stream>>>(
      gbuf, W2t, out, b2, x1buf, nullptr, nullptr, nullptr, 4096, 4096, 64);
}